// Round 11
// baseline (1876.650 us; speedup 1.0000x reference)
//
#include <hip/hip_runtime.h>

constexpr int NSTAY = 100000;
constexpr int NDIAG = 50000;
constexpr int NE    = 1000000;

constexpr int NB1   = 16;      // round-1 bins per type
constexpr int NB2   = 32;      // round-2 sub-bins per bin
constexpr int NR    = 512;     // ranges per type = NB1*NB2
constexpr int P1CAP = 65536;   // per-bin capacity   (mean 62500, sigma 242)
constexpr int P2CAP = 2400;    // per-range capacity (mean 1953,  sigma 44)
constexpr int BC1   = 160;     // LDS bin cap round 1 (mean 64/block, sigma 7.9)
constexpr int BC2   = 128;     // LDS bin cap round 2 (mean 32/block, sigma 5.6)

typedef __attribute__((ext_vector_type(8))) short bf16x8;
typedef __attribute__((ext_vector_type(4))) float f32x4;
typedef __attribute__((ext_vector_type(4))) float fvec4;
typedef __attribute__((ext_vector_type(4))) int   i32x4;

__device__ __forceinline__ float b2f(unsigned short u) {
  union { unsigned int i; float f; } v; v.i = (unsigned int)u << 16; return v.f;
}
__device__ __forceinline__ unsigned short f2b(float f) {
  union { float f; unsigned int i; } v; v.f = f;
  unsigned int r = (v.i + 0x7fffu + ((v.i >> 16) & 1u)) >> 16;   // RNE
  return (unsigned short)r;
}
__device__ __forceinline__ bf16x8 ldb8(const unsigned short* p) {
  return *reinterpret_cast<const bf16x8*>(p);
}
__device__ __forceinline__ f32x4 mfma16(bf16x8 a, bf16x8 b, f32x4 c) {
  return __builtin_amdgcn_mfma_f32_16x16x32_bf16(a, b, c, 0, 0, 0);
}

// ---------------- fused weight prep + gcur zeroing ----------------
__global__ __launch_bounds__(256) void k_prep(const float* __restrict__ Wps,
    const float* __restrict__ Wpd, const float* __restrict__ Wl,
    const float* __restrict__ Wr, unsigned short* __restrict__ Wps_b,
    unsigned short* __restrict__ Wpd_b, unsigned short* __restrict__ Wc6,
    int* __restrict__ gcur1, int* __restrict__ gcur2) {
  int i = blockIdx.x * 256 + threadIdx.x;
  if (i < 8192) {
    Wps_b[i] = f2b(Wps[i]);
  } else if (i < 12288) {
    Wpd_b[i - 8192] = f2b(Wpd[i - 8192]);
  } else if (i < 61440) {
    int t = i - 12288;
    int k = t & 127, f = (t >> 7) & 63, ty = t >> 13;
    float v = (k < 64) ? Wl[ty * 4096 + f * 64 + k] : Wr[ty * 4096 + f * 64 + (k - 64)];
    Wc6[t] = f2b(v);
  } else if (i < 61440 + 48) {
    gcur1[i - 61440] = 0;
  } else if (i < 61440 + 48 + 1536) {
    gcur2[i - 61440 - 48] = 0;
  }
}

// ---------------- MFMA input projection: out = relu(x @ Wb.T + b), K = NKC*32, x f32 (nt) ----------------
template<int NKC>
__global__ __launch_bounds__(256) void k_projM(const float* __restrict__ x,
    const unsigned short* __restrict__ Wb, const float* __restrict__ bias,
    unsigned short* __restrict__ out, int n) {
  const int lane = threadIdx.x & 63;
  const int wv   = threadIdx.x >> 6;
  const int r    = lane & 15;
  const int kg   = lane >> 4;
  const int tile0 = (blockIdx.x * 4 + wv) * 16;
  if (tile0 >= n) return;
  const int K = NKC * 32;
  bf16x8 Bf[4][NKC];
  #pragma unroll
  for (int nt = 0; nt < 4; ++nt)
    #pragma unroll
    for (int kc = 0; kc < NKC; ++kc)
      Bf[nt][kc] = ldb8(Wb + (nt * 16 + r) * K + kc * 32 + kg * 8);
  const int node = tile0 + r;
  const bool ok = node < n;
  bf16x8 Af[NKC] = {};
  if (ok) {
    #pragma unroll
    for (int kc = 0; kc < NKC; ++kc) {
      const float* px = x + (size_t)node * K + kc * 32 + kg * 8;
      fvec4 lo = __builtin_nontemporal_load(reinterpret_cast<const fvec4*>(px));
      fvec4 hi = __builtin_nontemporal_load(reinterpret_cast<const fvec4*>(px + 4));
      bf16x8 a;
      a[0] = (short)f2b(lo.x); a[1] = (short)f2b(lo.y);
      a[2] = (short)f2b(lo.z); a[3] = (short)f2b(lo.w);
      a[4] = (short)f2b(hi.x); a[5] = (short)f2b(hi.y);
      a[6] = (short)f2b(hi.z); a[7] = (short)f2b(hi.w);
      Af[kc] = a;
    }
  }
  f32x4 acc[4];
  #pragma unroll
  for (int nt = 0; nt < 4; ++nt) {
    f32x4 c = {0.f, 0.f, 0.f, 0.f};
    #pragma unroll
    for (int kc = 0; kc < NKC; ++kc)
      c = mfma16(Af[kc], Bf[nt][kc], c);
    acc[nt] = c;
  }
  #pragma unroll
  for (int j = 0; j < 4; ++j) {
    int m = tile0 + kg * 4 + j;
    if (m < n) {
      size_t base = (size_t)m * 64 + r;
      #pragma unroll
      for (int nt = 0; nt < 4; ++nt)
        out[base + nt * 16] = f2b(fmaxf(acc[nt][j] + bias[nt * 16 + r], 0.f));
    }
  }
}

// ---------------- partition round 1: 16 bins per type, LDS-staged coalesced flush ----------------
// grid 3*1024; packed u32 = (dchunkloc << 17) | src,  dchunkloc < cpc1 <= 6250 (13 bits), src < 2^17.
__global__ __launch_bounds__(256) void k_part1(
    const int* __restrict__ s0, const int* __restrict__ d0,
    const int* __restrict__ s1, const int* __restrict__ d1,
    const int* __restrict__ s2, const int* __restrict__ d2,
    unsigned int* __restrict__ part1, int* __restrict__ gcur1) {
  __shared__ unsigned int buf[NB1][BC1];
  __shared__ int bcnt[NB1];
  __shared__ int bbase[NB1];
  const int ty = blockIdx.x >> 10;
  const int bx = blockIdx.x & 1023;
  const int* src; const int* dst; int cpc1;
  if (ty == 0)      { src = s0; dst = d0; cpc1 = (NDIAG + NB1 - 1) / NB1; }
  else if (ty == 1) { src = s1; dst = d1; cpc1 = (NSTAY + NB1 - 1) / NB1; }
  else              { src = s2; dst = d2; cpc1 = (NSTAY + NB1 - 1) / NB1; }
  if (threadIdx.x < NB1) bcnt[threadIdx.x] = 0;
  __syncthreads();
  const int NE4 = NE / 4;
  int i = bx * 256 + threadIdx.x;
  if (i < NE4) {
    i32x4 dd = __builtin_nontemporal_load(reinterpret_cast<const i32x4*>(dst) + i);
    i32x4 ss = __builtin_nontemporal_load(reinterpret_cast<const i32x4*>(src) + i);
    #pragma unroll
    for (int u = 0; u < 4; ++u) {
      int d = dd[u];
      int b = d / cpc1;
      unsigned int pk = ((unsigned int)(d - b * cpc1) << 17) | (unsigned int)ss[u];
      int p = atomicAdd(&bcnt[b], 1);
      if (p < BC1) buf[b][p] = pk;
    }
  }
  __syncthreads();
  if (threadIdx.x < NB1) {
    int c = bcnt[threadIdx.x]; if (c > BC1) c = BC1;
    bcnt[threadIdx.x] = c;
    bbase[threadIdx.x] = atomicAdd(&gcur1[ty * NB1 + threadIdx.x], c);
  }
  __syncthreads();
  #pragma unroll
  for (int b = 0; b < NB1; ++b) {
    int c = bcnt[b], base = bbase[b];
    if (base > P1CAP - c) { int room = P1CAP - base; c = room > 0 ? room : 0; }
    unsigned int* op = part1 + ((size_t)ty * NB1 + b) * P1CAP + base;
    for (int t = threadIdx.x; t < c; t += 256)
      op[t] = buf[b][t];
  }
}

// ---------------- partition round 2: each bin -> 32 sub-bins (512 ranges/type) ----------------
// grid 3*16*64; packed u32 = (dloc << 17) | src, dloc < cpc2 <= 196 (8 bits).
__global__ __launch_bounds__(256) void k_part2(
    const unsigned int* __restrict__ part1, const int* __restrict__ gcur1,
    unsigned int* __restrict__ part2, int* __restrict__ gcur2) {
  __shared__ unsigned int buf[NB2][BC2];
  __shared__ int bcnt[NB2];
  __shared__ int bbase[NB2];
  const int gid = blockIdx.x;
  const int ty  = gid >> 10;
  const int bin = (gid >> 6) & 15;
  const int sub = gid & 63;
  const int cpc2 = (ty == 0) ? (((NDIAG + NB1 - 1) / NB1) + NB2 - 1) / NB2    // 98
                             : (((NSTAY + NB1 - 1) / NB1) + NB2 - 1) / NB2;   // 196
  int n1 = gcur1[ty * NB1 + bin]; if (n1 > P1CAP) n1 = P1CAP;
  const unsigned int* seg = part1 + ((size_t)ty * NB1 + bin) * P1CAP;
  if (threadIdx.x < NB2) bcnt[threadIdx.x] = 0;
  __syncthreads();
  int i4 = sub * 256 + threadIdx.x;                 // int4 index
  int i0 = i4 * 4;
  if (i0 + 4 <= n1) {
    i32x4 vv = *reinterpret_cast<const i32x4*>(seg + i0);
    #pragma unroll
    for (int u = 0; u < 4; ++u) {
      unsigned int v = (unsigned int)vv[u];
      int dcl = (int)(v >> 17);
      int sb = dcl / cpc2;
      unsigned int pk = ((unsigned int)(dcl - sb * cpc2) << 17) | (v & 0x1FFFFu);
      int p = atomicAdd(&bcnt[sb], 1);
      if (p < BC2) buf[sb][p] = pk;
    }
  } else {
    for (int u = 0; u < 4; ++u) {
      int idx = i0 + u;
      if (idx < n1) {
        unsigned int v = seg[idx];
        int dcl = (int)(v >> 17);
        int sb = dcl / cpc2;
        unsigned int pk = ((unsigned int)(dcl - sb * cpc2) << 17) | (v & 0x1FFFFu);
        int p = atomicAdd(&bcnt[sb], 1);
        if (p < BC2) buf[sb][p] = pk;
      }
    }
  }
  __syncthreads();
  if (threadIdx.x < NB2) {
    int c = bcnt[threadIdx.x]; if (c > BC2) c = BC2;
    bcnt[threadIdx.x] = c;
    bbase[threadIdx.x] = atomicAdd(&gcur2[ty * NR + bin * NB2 + threadIdx.x], c);
  }
  __syncthreads();
  #pragma unroll
  for (int b = 0; b < NB2; ++b) {
    int c = bcnt[b], base = bbase[b];
    if (base > P2CAP - c) { int room = P2CAP - base; c = room > 0 ? room : 0; }
    unsigned int* op = part2 + ((size_t)ty * NR + bin * NB2 + b) * P2CAP + base;
    for (int t = threadIdx.x; t < c; t += 256)
      op[t] = buf[b][t];
  }
}

// ---------------- LDS-accumulated gather-mean: one workgroup per (type, range) ----------------
// f32 accumulators in LDS; per edge: 1 coalesced 128B h-row read + 64-lane ds_add_f32.
// Output agg writes fully coalesced. tyoff=1 skips the dead s2d type in layer 1.
__global__ __launch_bounds__(512) void k_agg(
    const unsigned int* __restrict__ part2, const int* __restrict__ gcur2,
    const unsigned short* __restrict__ hs, const unsigned short* __restrict__ hd,
    unsigned short* __restrict__ aggD, unsigned short* __restrict__ agg1,
    unsigned short* __restrict__ agg2, int tyoff) {
  __shared__ float acc[196 * 64];    // 50.2 KB (diag ranges use first 98 rows)
  __shared__ int cntL[196];
  const int ty = tyoff + (int)(blockIdx.x >> 9);
  const int r  = blockIdx.x & (NR - 1);
  const unsigned short* h; unsigned short* agg; int cpc1, cpc2, nnode;
  if (ty == 0)      { h = hs; agg = aggD; cpc1 = 3125; cpc2 = 98;  nnode = NDIAG; }
  else if (ty == 1) { h = hd; agg = agg1; cpc1 = 6250; cpc2 = 196; nnode = NSTAY; }
  else              { h = hs; agg = agg2; cpc1 = 6250; cpc2 = 196; nnode = NSTAY; }
  const int nacc = cpc2 * 64;
  for (int i = threadIdx.x; i < nacc; i += 512) acc[i] = 0.f;
  for (int i = threadIdx.x; i < cpc2; i += 512) cntL[i] = 0;
  __syncthreads();
  const int rid = ty * NR + r;
  int n2 = gcur2[rid]; if (n2 > P2CAP) n2 = P2CAP;
  const unsigned int* seg = part2 + (size_t)rid * P2CAP;
  const int lane = threadIdx.x & 63;
  const int w    = threadIdx.x >> 6;          // 8 waves
  for (int j0 = w * 8; j0 < n2; j0 += 64) {
    int m = n2 - j0; if (m > 8) m = 8;
    if (m == 8) {
      unsigned int e0 = seg[j0],     e1 = seg[j0 + 1], e2 = seg[j0 + 2], e3 = seg[j0 + 3];
      unsigned int e4 = seg[j0 + 4], e5 = seg[j0 + 5], e6 = seg[j0 + 6], e7 = seg[j0 + 7];
      float v0 = b2f(h[(size_t)(e0 & 0x1FFFFu) * 64 + lane]);
      float v1 = b2f(h[(size_t)(e1 & 0x1FFFFu) * 64 + lane]);
      float v2 = b2f(h[(size_t)(e2 & 0x1FFFFu) * 64 + lane]);
      float v3 = b2f(h[(size_t)(e3 & 0x1FFFFu) * 64 + lane]);
      float v4 = b2f(h[(size_t)(e4 & 0x1FFFFu) * 64 + lane]);
      float v5 = b2f(h[(size_t)(e5 & 0x1FFFFu) * 64 + lane]);
      float v6 = b2f(h[(size_t)(e6 & 0x1FFFFu) * 64 + lane]);
      float v7 = b2f(h[(size_t)(e7 & 0x1FFFFu) * 64 + lane]);
      atomicAdd(&acc[(e0 >> 17) * 64 + lane], v0);
      atomicAdd(&acc[(e1 >> 17) * 64 + lane], v1);
      atomicAdd(&acc[(e2 >> 17) * 64 + lane], v2);
      atomicAdd(&acc[(e3 >> 17) * 64 + lane], v3);
      atomicAdd(&acc[(e4 >> 17) * 64 + lane], v4);
      atomicAdd(&acc[(e5 >> 17) * 64 + lane], v5);
      atomicAdd(&acc[(e6 >> 17) * 64 + lane], v6);
      atomicAdd(&acc[(e7 >> 17) * 64 + lane], v7);
      if (lane == 0) {
        atomicAdd(&cntL[e0 >> 17], 1); atomicAdd(&cntL[e1 >> 17], 1);
        atomicAdd(&cntL[e2 >> 17], 1); atomicAdd(&cntL[e3 >> 17], 1);
        atomicAdd(&cntL[e4 >> 17], 1); atomicAdd(&cntL[e5 >> 17], 1);
        atomicAdd(&cntL[e6 >> 17], 1); atomicAdd(&cntL[e7 >> 17], 1);
      }
    } else {
      for (int u = 0; u < m; ++u) {
        unsigned int e = seg[j0 + u];
        float v = b2f(h[(size_t)(e & 0x1FFFFu) * 64 + lane]);
        atomicAdd(&acc[(e >> 17) * 64 + lane], v);
        if (lane == 0) atomicAdd(&cntL[e >> 17], 1);
      }
    }
  }
  __syncthreads();
  const int bin = r >> 5, sb = r & 31;
  const int node0 = bin * cpc1 + sb * cpc2;
  const int dmax_in_bin = cpc1 - sb * cpc2;      // rows beyond this alias the next bin
  for (int idx = threadIdx.x; idx < nacc; idx += 512) {
    int dloc = idx >> 6, f = idx & 63;
    int node = node0 + dloc;
    if (dloc < dmax_in_bin && node < nnode) {
      int c = cntL[dloc];
      float inv = (c > 0) ? 1.0f / (float)c : 1.0f;
      agg[(size_t)node * 64 + f] = f2b(acc[idx] * inv);
    }
  }
}

// ---------------- fused stay-side SAGE: two edge types + hetero-mean + relu + LN (+cls) ----------------
template<int CLS>
__global__ __launch_bounds__(256) void k_sage2(
    const unsigned short* __restrict__ agg2b,
    const unsigned short* __restrict__ agg1b,
    unsigned short* hb,
    const unsigned short* __restrict__ W2b, const float* __restrict__ bl2,
    const unsigned short* __restrict__ W1b, const float* __restrict__ bl1,
    const float* __restrict__ g, const float* __restrict__ bln, int n,
    const float* __restrict__ Wcf, const float* __restrict__ bcf,
    float* __restrict__ outp) {
  const int lane = threadIdx.x & 63;
  const int wv   = threadIdx.x >> 6;
  const int r    = lane & 15;
  const int kg   = lane >> 4;
  const int tile0 = (blockIdx.x * 4 + wv) * 16;
  if (tile0 >= n) return;
  const int node = tile0 + r;
  const bool ok = node < n;
  const size_t rowa = (size_t)node * 64 + kg * 8;
  bf16x8 A20 = {}, A21 = {}, A10 = {}, A11 = {}, H0 = {}, H1 = {};
  if (ok) {
    A20 = ldb8(agg2b + rowa); A21 = ldb8(agg2b + rowa + 32);
    A10 = ldb8(agg1b + rowa); A11 = ldb8(agg1b + rowa + 32);
    H0  = ldb8(hb + rowa);    H1  = ldb8(hb + rowa + 32);
  }
  f32x4 acc2[4], acc1[4];
  #pragma unroll
  for (int nt = 0; nt < 4; ++nt) {
    const unsigned short* wr = W2b + (nt * 16 + r) * 128 + kg * 8;
    f32x4 c = {0.f, 0.f, 0.f, 0.f};
    c = mfma16(A20, ldb8(wr), c);
    c = mfma16(A21, ldb8(wr + 32), c);
    c = mfma16(H0,  ldb8(wr + 64), c);
    c = mfma16(H1,  ldb8(wr + 96), c);
    acc2[nt] = c;
  }
  #pragma unroll
  for (int nt = 0; nt < 4; ++nt) {
    const unsigned short* wr = W1b + (nt * 16 + r) * 128 + kg * 8;
    f32x4 c = {0.f, 0.f, 0.f, 0.f};
    c = mfma16(A10, ldb8(wr), c);
    c = mfma16(A11, ldb8(wr + 32), c);
    c = mfma16(H0,  ldb8(wr + 64), c);
    c = mfma16(H1,  ldb8(wr + 96), c);
    acc1[nt] = c;
  }
  #pragma unroll
  for (int nt = 0; nt < 4; ++nt) {
    float b2 = bl2[nt * 16 + r], b1 = bl1[nt * 16 + r];
    #pragma unroll
    for (int j = 0; j < 4; ++j) { acc2[nt][j] += b2; acc1[nt][j] += b1; }
  }
  float ss2[4], ss1[4];
  #pragma unroll
  for (int j = 0; j < 4; ++j) {
    ss2[j] = acc2[0][j] * acc2[0][j] + acc2[1][j] * acc2[1][j]
           + acc2[2][j] * acc2[2][j] + acc2[3][j] * acc2[3][j];
    ss1[j] = acc1[0][j] * acc1[0][j] + acc1[1][j] * acc1[1][j]
           + acc1[2][j] * acc1[2][j] + acc1[3][j] * acc1[3][j];
  }
  #pragma unroll
  for (int off = 1; off < 16; off <<= 1) {
    #pragma unroll
    for (int j = 0; j < 4; ++j) {
      ss2[j] += __shfl_xor(ss2[j], off);
      ss1[j] += __shfl_xor(ss1[j], off);
    }
  }
  float v[4][4];
  #pragma unroll
  for (int j = 0; j < 4; ++j) {
    float ri2 = 1.0f / fmaxf(sqrtf(ss2[j]), 1e-12f);
    float ri1 = 1.0f / fmaxf(sqrtf(ss1[j]), 1e-12f);
    #pragma unroll
    for (int nt = 0; nt < 4; ++nt)
      v[nt][j] = fmaxf(0.5f * (acc2[nt][j] * ri2 + acc1[nt][j] * ri1), 0.f);
  }
  float s1[4], s2[4];
  #pragma unroll
  for (int j = 0; j < 4; ++j) {
    s1[j] = v[0][j] + v[1][j] + v[2][j] + v[3][j];
    s2[j] = v[0][j] * v[0][j] + v[1][j] * v[1][j] + v[2][j] * v[2][j] + v[3][j] * v[3][j];
  }
  #pragma unroll
  for (int off = 1; off < 16; off <<= 1) {
    #pragma unroll
    for (int j = 0; j < 4; ++j) {
      s1[j] += __shfl_xor(s1[j], off);
      s2[j] += __shfl_xor(s2[j], off);
    }
  }
  if (CLS == 0) {
    #pragma unroll
    for (int j = 0; j < 4; ++j) {
      int m = tile0 + kg * 4 + j;
      if (m >= n) continue;
      float mu  = s1[j] * (1.f / 64.f);
      float var = s2[j] * (1.f / 64.f) - mu * mu;
      float is  = 1.0f / sqrtf(var + 1e-5f);
      size_t base = (size_t)m * 64 + r;
      #pragma unroll
      for (int nt = 0; nt < 4; ++nt)
        hb[base + nt * 16] = f2b((v[nt][j] - mu) * is * g[nt * 16 + r] + bln[nt * 16 + r]);
    }
  } else {
    float wcc[3][4];
    #pragma unroll
    for (int c = 0; c < 3; ++c)
      #pragma unroll
      for (int nt = 0; nt < 4; ++nt) wcc[c][nt] = Wcf[c * 64 + nt * 16 + r];
    #pragma unroll
    for (int j = 0; j < 4; ++j) {
      int m = tile0 + kg * 4 + j;
      float mu  = s1[j] * (1.f / 64.f);
      float var = s2[j] * (1.f / 64.f) - mu * mu;
      float is  = 1.0f / sqrtf(var + 1e-5f);
      float p0 = 0.f, p1 = 0.f, p2 = 0.f;
      #pragma unroll
      for (int nt = 0; nt < 4; ++nt) {
        float hv = (v[nt][j] - mu) * is * g[nt * 16 + r] + bln[nt * 16 + r];
        p0 += hv * wcc[0][nt]; p1 += hv * wcc[1][nt]; p2 += hv * wcc[2][nt];
      }
      #pragma unroll
      for (int off = 1; off < 16; off <<= 1) {
        p0 += __shfl_xor(p0, off);
        p1 += __shfl_xor(p1, off);
        p2 += __shfl_xor(p2, off);
      }
      if (m < n && r < 3) {
        float pr = (r == 0) ? p0 : ((r == 1) ? p1 : p2);
        outp[(size_t)m * 3 + r] = pr + bcf[r];
      }
    }
  }
}

// ---------------- diag-side SAGE (single edge type) + relu + LN, in-place ----------------
__global__ __launch_bounds__(256) void k_sageD(
    const unsigned short* __restrict__ aggb,
    unsigned short* hb,
    const unsigned short* __restrict__ Wb, const float* __restrict__ bl,
    const float* __restrict__ g, const float* __restrict__ bln, int n) {
  const int lane = threadIdx.x & 63;
  const int wv   = threadIdx.x >> 6;
  const int r    = lane & 15;
  const int kg   = lane >> 4;
  const int tile0 = (blockIdx.x * 4 + wv) * 16;
  if (tile0 >= n) return;
  const int node = tile0 + r;
  const bool ok = node < n;
  const size_t rowa = (size_t)node * 64 + kg * 8;
  bf16x8 A0 = {}, A1 = {}, H0 = {}, H1 = {};
  if (ok) {
    A0 = ldb8(aggb + rowa); A1 = ldb8(aggb + rowa + 32);
    H0 = ldb8(hb + rowa);   H1 = ldb8(hb + rowa + 32);
  }
  f32x4 acc[4];
  #pragma unroll
  for (int nt = 0; nt < 4; ++nt) {
    const unsigned short* wr = Wb + (nt * 16 + r) * 128 + kg * 8;
    f32x4 c = {0.f, 0.f, 0.f, 0.f};
    c = mfma16(A0, ldb8(wr), c);
    c = mfma16(A1, ldb8(wr + 32), c);
    c = mfma16(H0, ldb8(wr + 64), c);
    c = mfma16(H1, ldb8(wr + 96), c);
    acc[nt] = c;
  }
  #pragma unroll
  for (int nt = 0; nt < 4; ++nt) {
    float bb = bl[nt * 16 + r];
    #pragma unroll
    for (int j = 0; j < 4; ++j) acc[nt][j] += bb;
  }
  float ss[4];
  #pragma unroll
  for (int j = 0; j < 4; ++j)
    ss[j] = acc[0][j] * acc[0][j] + acc[1][j] * acc[1][j]
          + acc[2][j] * acc[2][j] + acc[3][j] * acc[3][j];
  #pragma unroll
  for (int off = 1; off < 16; off <<= 1) {
    #pragma unroll
    for (int j = 0; j < 4; ++j) ss[j] += __shfl_xor(ss[j], off);
  }
  float v[4][4];
  #pragma unroll
  for (int j = 0; j < 4; ++j) {
    float ri = 1.0f / fmaxf(sqrtf(ss[j]), 1e-12f);
    #pragma unroll
    for (int nt = 0; nt < 4; ++nt) v[nt][j] = fmaxf(acc[nt][j] * ri, 0.f);
  }
  float s1[4], s2[4];
  #pragma unroll
  for (int j = 0; j < 4; ++j) {
    s1[j] = v[0][j] + v[1][j] + v[2][j] + v[3][j];
    s2[j] = v[0][j] * v[0][j] + v[1][j] * v[1][j] + v[2][j] * v[2][j] + v[3][j] * v[3][j];
  }
  #pragma unroll
  for (int off = 1; off < 16; off <<= 1) {
    #pragma unroll
    for (int j = 0; j < 4; ++j) {
      s1[j] += __shfl_xor(s1[j], off);
      s2[j] += __shfl_xor(s2[j], off);
    }
  }
  #pragma unroll
  for (int j = 0; j < 4; ++j) {
    int m = tile0 + kg * 4 + j;
    if (m >= n) continue;
    float mu  = s1[j] * (1.f / 64.f);
    float var = s2[j] * (1.f / 64.f) - mu * mu;
    float is  = 1.0f / sqrtf(var + 1e-5f);
    size_t base = (size_t)m * 64 + r;
    #pragma unroll
    for (int nt = 0; nt < 4; ++nt)
      hb[base + nt * 16] = f2b((v[nt][j] - mu) * is * g[nt * 16 + r] + bln[nt * 16 + r]);
  }
}

extern "C" void kernel_launch(void* const* d_in, const int* in_sizes, int n_in,
                              void* d_out, int out_size, void* d_ws, size_t ws_size,
                              hipStream_t stream) {
  const float* x_stay  = (const float*)d_in[0];
  const float* x_diag  = (const float*)d_in[1];
  const int*   s2d_src = (const int*)d_in[2];
  const int*   s2d_dst = (const int*)d_in[3];
  const int*   d2s_src = (const int*)d_in[4];
  const int*   d2s_dst = (const int*)d_in[5];
  const int*   s2s_src = (const int*)d_in[6];
  const int*   s2s_dst = (const int*)d_in[7];
  const float* Wp_stay = (const float*)d_in[8];
  const float* bp_stay = (const float*)d_in[9];
  const float* Wp_diag = (const float*)d_in[10];
  const float* bp_diag = (const float*)d_in[11];
  const float* Wl      = (const float*)d_in[12];
  const float* bl      = (const float*)d_in[13];
  const float* Wr      = (const float*)d_in[14];
  const float* ln_g    = (const float*)d_in[15];
  const float* ln_b    = (const float*)d_in[16];
  const float* Wc      = (const float*)d_in[17];
  const float* bc      = (const float*)d_in[18];

  // ---- workspace layout (float-slot units) ----
  float* ws = (float*)d_ws;
  unsigned short* hs_b   = (unsigned short*)(ws);             // 6.4M ush
  unsigned short* hd_b   = (unsigned short*)(ws + 3200000);   // 3.2M ush
  unsigned short* agg2_b = (unsigned short*)(ws + 4800000);   // 6.4M ush
  unsigned short* agg1_b = (unsigned short*)(ws + 8000000);   // 6.4M ush
  unsigned short* aggD_b = (unsigned short*)(ws + 11200000);  // 3.2M ush
  unsigned short* Wc6    = (unsigned short*)(ws + 12800000);  // 49152 ush
  unsigned short* Wps_b  = (unsigned short*)(ws + 12825000);  // 8192 ush
  unsigned short* Wpd_b  = (unsigned short*)(ws + 12830000);  // 4096 ush
  unsigned int* part1 = (unsigned int*)(ws + 12835000);       // 3*16*65536 = 3,145,728 slots
  unsigned int* part2 = (unsigned int*)(ws + 15985000);       // 3*512*2400 = 3,686,400 slots
  int* gcur1 = (int*)(ws + 19675000);                         // 48
  int* gcur2 = gcur1 + 48;                                    // 1536
  // end ≈ 19.68M slots ≈ 78.7 MB

  // ---- weight prep + gcur zeroing ----
  k_prep<<<247, 256, 0, stream>>>(Wp_stay, Wp_diag, Wl, Wr, Wps_b, Wpd_b, Wc6,
                                  gcur1, gcur2);

  // ---- two-round coalesced partition (replaces bucket scatter; built once) ----
  k_part1<<<3072, 256, 0, stream>>>(s2d_src, s2d_dst, d2s_src, d2s_dst,
                                    s2s_src, s2s_dst, part1, gcur1);
  k_part2<<<3072, 256, 0, stream>>>(part1, gcur1, part2, gcur2);

  // ---- input projections (MFMA, f32 nt in, bf16 out) ----
  k_projM<4><<<1563, 256, 0, stream>>>(x_stay, Wps_b, bp_stay, hs_b, NSTAY);
  k_projM<2><<<782, 256, 0, stream>>>(x_diag, Wpd_b, bp_diag, hd_b, NDIAG);

  const int GS = (NSTAY / 16 + 3) / 4;   // 1563
  const int GD = (NDIAG / 16 + 3) / 4;   // 782

  // ================= layer 0 =================
  {
    const unsigned short* W0 = Wc6;
    const unsigned short* W1 = Wc6 + 8192;
    const unsigned short* W2 = Wc6 + 16384;
    const float* bl0 = bl, *bl1 = bl + 64, *bl2 = bl + 128;
    const float* g = ln_g, *b = ln_b;

    k_agg<<<3 * NR, 512, 0, stream>>>(part2, gcur2, hs_b, hd_b,
                                      aggD_b, agg1_b, agg2_b, 0);
    k_sage2<0><<<GS, 256, 0, stream>>>(agg2_b, agg1_b, hs_b, W2, bl2, W1, bl1,
        g, b, NSTAY, nullptr, nullptr, nullptr);
    k_sageD<<<GD, 256, 0, stream>>>(aggD_b, hd_b, W0, bl0, g, b, NDIAG);
  }
  // ================= layer 1 (diag update dead: output depends only on h_stay) =================
  {
    const unsigned short* W1 = Wc6 + 8192 * 4;   // type 1, layer 1
    const unsigned short* W2 = Wc6 + 8192 * 5;   // type 2, layer 1
    const float* bl1 = bl + (3 + 1) * 64;
    const float* bl2 = bl + (3 + 2) * 64;
    const float* g = ln_g + 64, *b = ln_b + 64;

    k_agg<<<2 * NR, 512, 0, stream>>>(part2, gcur2, hs_b, hd_b,
                                      aggD_b, agg1_b, agg2_b, 1);
    k_sage2<1><<<GS, 256, 0, stream>>>(agg2_b, agg1_b, hs_b, W2, bl2, W1, bl1,
        g, b, NSTAY, Wc, bc, (float*)d_out);
  }
}

// Round 12
// 347.830 us; speedup vs baseline: 5.3953x; 5.3953x over previous
//
#include <hip/hip_runtime.h>

constexpr int NSTAY = 100000;
constexpr int NDIAG = 50000;
constexpr int NE    = 1000000;

constexpr int NB1   = 16;      // round-1 bins per type
constexpr int NB2   = 32;      // round-2 sub-bins per bin
constexpr int NR    = 512;     // ranges per type = NB1*NB2
constexpr int P1CAP = 65536;   // per-bin capacity   (mean 62500, sigma 242)
constexpr int P2CAP = 2400;    // per-range capacity (mean 1953,  sigma 44)
constexpr int BC1   = 160;     // LDS bin cap round 1
constexpr int BC2   = 128;     // LDS bin cap round 2

typedef __attribute__((ext_vector_type(8))) short bf16x8;
typedef __attribute__((ext_vector_type(4))) float f32x4;
typedef __attribute__((ext_vector_type(4))) float fvec4;
typedef __attribute__((ext_vector_type(4))) int   i32x4;

__device__ __forceinline__ float b2f(unsigned short u) {
  union { unsigned int i; float f; } v; v.i = (unsigned int)u << 16; return v.f;
}
__device__ __forceinline__ unsigned short f2b(float f) {
  union { float f; unsigned int i; } v; v.f = f;
  unsigned int r = (v.i + 0x7fffu + ((v.i >> 16) & 1u)) >> 16;   // RNE
  return (unsigned short)r;
}
__device__ __forceinline__ bf16x8 ldb8(const unsigned short* p) {
  return *reinterpret_cast<const bf16x8*>(p);
}
__device__ __forceinline__ f32x4 mfma16(bf16x8 a, bf16x8 b, f32x4 c) {
  return __builtin_amdgcn_mfma_f32_16x16x32_bf16(a, b, c, 0, 0, 0);
}

// ---------------- fused weight prep + gcur zeroing ----------------
__global__ __launch_bounds__(256) void k_prep(const float* __restrict__ Wps,
    const float* __restrict__ Wpd, const float* __restrict__ Wl,
    const float* __restrict__ Wr, unsigned short* __restrict__ Wps_b,
    unsigned short* __restrict__ Wpd_b, unsigned short* __restrict__ Wc6,
    int* __restrict__ gcur1, int* __restrict__ gcur2) {
  int i = blockIdx.x * 256 + threadIdx.x;
  if (i < 8192) {
    Wps_b[i] = f2b(Wps[i]);
  } else if (i < 12288) {
    Wpd_b[i - 8192] = f2b(Wpd[i - 8192]);
  } else if (i < 61440) {
    int t = i - 12288;
    int k = t & 127, f = (t >> 7) & 63, ty = t >> 13;
    float v = (k < 64) ? Wl[ty * 4096 + f * 64 + k] : Wr[ty * 4096 + f * 64 + (k - 64)];
    Wc6[t] = f2b(v);
  } else if (i < 61440 + 48) {
    gcur1[i - 61440] = 0;
  } else if (i < 61440 + 48 + 1536) {
    gcur2[i - 61440 - 48] = 0;
  }
}

// ---------------- MFMA input projection: out = relu(x @ Wb.T + b), K = NKC*32, x f32 (nt) ----------------
template<int NKC>
__global__ __launch_bounds__(256) void k_projM(const float* __restrict__ x,
    const unsigned short* __restrict__ Wb, const float* __restrict__ bias,
    unsigned short* __restrict__ out, int n) {
  const int lane = threadIdx.x & 63;
  const int wv   = threadIdx.x >> 6;
  const int r    = lane & 15;
  const int kg   = lane >> 4;
  const int tile0 = (blockIdx.x * 4 + wv) * 16;
  if (tile0 >= n) return;
  const int K = NKC * 32;
  bf16x8 Bf[4][NKC];
  #pragma unroll
  for (int nt = 0; nt < 4; ++nt)
    #pragma unroll
    for (int kc = 0; kc < NKC; ++kc)
      Bf[nt][kc] = ldb8(Wb + (nt * 16 + r) * K + kc * 32 + kg * 8);
  const int node = tile0 + r;
  const bool ok = node < n;
  bf16x8 Af[NKC] = {};
  if (ok) {
    #pragma unroll
    for (int kc = 0; kc < NKC; ++kc) {
      const float* px = x + (size_t)node * K + kc * 32 + kg * 8;
      fvec4 lo = __builtin_nontemporal_load(reinterpret_cast<const fvec4*>(px));
      fvec4 hi = __builtin_nontemporal_load(reinterpret_cast<const fvec4*>(px + 4));
      bf16x8 a;
      a[0] = (short)f2b(lo.x); a[1] = (short)f2b(lo.y);
      a[2] = (short)f2b(lo.z); a[3] = (short)f2b(lo.w);
      a[4] = (short)f2b(hi.x); a[5] = (short)f2b(hi.y);
      a[6] = (short)f2b(hi.z); a[7] = (short)f2b(hi.w);
      Af[kc] = a;
    }
  }
  f32x4 acc[4];
  #pragma unroll
  for (int nt = 0; nt < 4; ++nt) {
    f32x4 c = {0.f, 0.f, 0.f, 0.f};
    #pragma unroll
    for (int kc = 0; kc < NKC; ++kc)
      c = mfma16(Af[kc], Bf[nt][kc], c);
    acc[nt] = c;
  }
  #pragma unroll
  for (int j = 0; j < 4; ++j) {
    int m = tile0 + kg * 4 + j;
    if (m < n) {
      size_t base = (size_t)m * 64 + r;
      #pragma unroll
      for (int nt = 0; nt < 4; ++nt)
        out[base + nt * 16] = f2b(fmaxf(acc[nt][j] + bias[nt * 16 + r], 0.f));
    }
  }
}

// ---------------- partition round 1: 16 bins per type (LDS int atomics + coalesced flush) ----------------
__global__ __launch_bounds__(256) void k_part1(
    const int* __restrict__ s0, const int* __restrict__ d0,
    const int* __restrict__ s1, const int* __restrict__ d1,
    const int* __restrict__ s2, const int* __restrict__ d2,
    unsigned int* __restrict__ part1, int* __restrict__ gcur1) {
  __shared__ unsigned int buf[NB1][BC1];
  __shared__ int bcnt[NB1];
  __shared__ int bbase[NB1];
  const int ty = blockIdx.x >> 10;
  const int bx = blockIdx.x & 1023;
  const int* src; const int* dst; int cpc1;
  if (ty == 0)      { src = s0; dst = d0; cpc1 = (NDIAG + NB1 - 1) / NB1; }
  else if (ty == 1) { src = s1; dst = d1; cpc1 = (NSTAY + NB1 - 1) / NB1; }
  else              { src = s2; dst = d2; cpc1 = (NSTAY + NB1 - 1) / NB1; }
  if (threadIdx.x < NB1) bcnt[threadIdx.x] = 0;
  __syncthreads();
  const int NE4 = NE / 4;
  int i = bx * 256 + threadIdx.x;
  if (i < NE4) {
    i32x4 dd = __builtin_nontemporal_load(reinterpret_cast<const i32x4*>(dst) + i);
    i32x4 ss = __builtin_nontemporal_load(reinterpret_cast<const i32x4*>(src) + i);
    #pragma unroll
    for (int u = 0; u < 4; ++u) {
      int d = dd[u];
      int b = d / cpc1;
      unsigned int pk = ((unsigned int)(d - b * cpc1) << 17) | (unsigned int)ss[u];
      int p = atomicAdd(&bcnt[b], 1);
      if (p < BC1) buf[b][p] = pk;
    }
  }
  __syncthreads();
  if (threadIdx.x < NB1) {
    int c = bcnt[threadIdx.x]; if (c > BC1) c = BC1;
    bcnt[threadIdx.x] = c;
    bbase[threadIdx.x] = atomicAdd(&gcur1[ty * NB1 + threadIdx.x], c);
  }
  __syncthreads();
  #pragma unroll
  for (int b = 0; b < NB1; ++b) {
    int c = bcnt[b], base = bbase[b];
    if (base > P1CAP - c) { int room = P1CAP - base; c = room > 0 ? room : 0; }
    unsigned int* op = part1 + ((size_t)ty * NB1 + b) * P1CAP + base;
    for (int t = threadIdx.x; t < c; t += 256)
      op[t] = buf[b][t];
  }
}

// ---------------- partition round 2: each bin -> 32 sub-bins (512 ranges/type) ----------------
__global__ __launch_bounds__(256) void k_part2(
    const unsigned int* __restrict__ part1, const int* __restrict__ gcur1,
    unsigned int* __restrict__ part2, int* __restrict__ gcur2) {
  __shared__ unsigned int buf[NB2][BC2];
  __shared__ int bcnt[NB2];
  __shared__ int bbase[NB2];
  const int gid = blockIdx.x;
  const int ty  = gid >> 10;
  const int bin = (gid >> 6) & 15;
  const int sub = gid & 63;
  const int cpc2 = (ty == 0) ? 98 : 196;
  int n1 = gcur1[ty * NB1 + bin]; if (n1 > P1CAP) n1 = P1CAP;
  const unsigned int* seg = part1 + ((size_t)ty * NB1 + bin) * P1CAP;
  if (threadIdx.x < NB2) bcnt[threadIdx.x] = 0;
  __syncthreads();
  int i4 = sub * 256 + threadIdx.x;
  int i0 = i4 * 4;
  if (i0 + 4 <= n1) {
    i32x4 vv = *reinterpret_cast<const i32x4*>(seg + i0);
    #pragma unroll
    for (int u = 0; u < 4; ++u) {
      unsigned int v = (unsigned int)vv[u];
      int dcl = (int)(v >> 17);
      int sb = dcl / cpc2;
      unsigned int pk = ((unsigned int)(dcl - sb * cpc2) << 17) | (v & 0x1FFFFu);
      int p = atomicAdd(&bcnt[sb], 1);
      if (p < BC2) buf[sb][p] = pk;
    }
  } else {
    for (int u = 0; u < 4; ++u) {
      int idx = i0 + u;
      if (idx < n1) {
        unsigned int v = seg[idx];
        int dcl = (int)(v >> 17);
        int sb = dcl / cpc2;
        unsigned int pk = ((unsigned int)(dcl - sb * cpc2) << 17) | (v & 0x1FFFFu);
        int p = atomicAdd(&bcnt[sb], 1);
        if (p < BC2) buf[sb][p] = pk;
      }
    }
  }
  __syncthreads();
  if (threadIdx.x < NB2) {
    int c = bcnt[threadIdx.x]; if (c > BC2) c = BC2;
    bcnt[threadIdx.x] = c;
    bbase[threadIdx.x] = atomicAdd(&gcur2[ty * NR + bin * NB2 + threadIdx.x], c);
  }
  __syncthreads();
  #pragma unroll
  for (int b = 0; b < NB2; ++b) {
    int c = bcnt[b], base = bbase[b];
    if (base > P2CAP - c) { int room = P2CAP - base; c = room > 0 ? room : 0; }
    unsigned int* op = part2 + ((size_t)ty * NR + bin * NB2 + b) * P2CAP + base;
    for (int t = threadIdx.x; t < c; t += 256)
      op[t] = buf[b][t];
  }
}

// ---------------- CSR build per range: count (int LDS atomics) -> scan -> sort in LDS -> coalesced flush ----------------
// Sorts each part2 segment by dst in place (keeps only src), writes off/deg per node. NO scattered global stores.
__global__ __launch_bounds__(256) void k_csr(
    unsigned int* __restrict__ part2, const int* __restrict__ gcur2,
    int* __restrict__ offD, int* __restrict__ degD,
    int* __restrict__ off1, int* __restrict__ deg1,
    int* __restrict__ off2, int* __restrict__ deg2) {
  __shared__ int cnt[196];
  __shared__ int cur[196];
  __shared__ unsigned int sorted[P2CAP];
  const int ty = blockIdx.x >> 9;
  const int r  = blockIdx.x & (NR - 1);
  int cpc1, cpc2, nnode; int* off; int* deg;
  if (ty == 0)      { cpc1 = 3125; cpc2 = 98;  nnode = NDIAG; off = offD; deg = degD; }
  else if (ty == 1) { cpc1 = 6250; cpc2 = 196; nnode = NSTAY; off = off1; deg = deg1; }
  else              { cpc1 = 6250; cpc2 = 196; nnode = NSTAY; off = off2; deg = deg2; }
  const int rid = ty * NR + r;
  int n2 = gcur2[rid]; if (n2 > P2CAP) n2 = P2CAP;
  unsigned int* seg = part2 + (size_t)rid * P2CAP;
  for (int i = threadIdx.x; i < cpc2; i += 256) cnt[i] = 0;
  __syncthreads();
  for (int t = threadIdx.x; t < n2; t += 256)
    atomicAdd(&cnt[seg[t] >> 17], 1);
  __syncthreads();
  // exclusive scan of cnt[0..cpc2) by wave 0 (4 elems/lane + shfl_up)
  if (threadIdx.x < 64) {
    int lane = threadIdx.x;
    int c0 = (lane * 4     < cpc2) ? cnt[lane * 4]     : 0;
    int c1 = (lane * 4 + 1 < cpc2) ? cnt[lane * 4 + 1] : 0;
    int c2 = (lane * 4 + 2 < cpc2) ? cnt[lane * 4 + 2] : 0;
    int c3 = (lane * 4 + 3 < cpc2) ? cnt[lane * 4 + 3] : 0;
    int qs = c0 + c1 + c2 + c3;
    int x = qs;
    #pragma unroll
    for (int o = 1; o < 64; o <<= 1) { int y = __shfl_up(x, o); if (lane >= o) x += y; }
    int base = x - qs;
    if (lane * 4     < cpc2) cur[lane * 4]     = base;
    if (lane * 4 + 1 < cpc2) cur[lane * 4 + 1] = base + c0;
    if (lane * 4 + 2 < cpc2) cur[lane * 4 + 2] = base + c0 + c1;
    if (lane * 4 + 3 < cpc2) cur[lane * 4 + 3] = base + c0 + c1 + c2;
  }
  __syncthreads();
  // write off/deg (coalesced) BEFORE cur is bumped
  const int bin = r >> 5, sb = r & 31;
  const int node0 = bin * cpc1 + sb * cpc2;
  int dmax = cpc1 - sb * cpc2; if (dmax > cpc2) dmax = cpc2;
  for (int i = threadIdx.x; i < cpc2; i += 256) {
    int node = node0 + i;
    if (i < dmax && node < nnode) {
      off[node] = rid * P2CAP + cur[i];
      deg[node] = cnt[i];
    }
  }
  __syncthreads();
  // place into LDS sorted (int LDS atomics), then coalesced in-place flush
  for (int t = threadIdx.x; t < n2; t += 256) {
    unsigned int v = seg[t];
    int pos = atomicAdd(&cur[v >> 17], 1);
    sorted[pos] = v & 0x1FFFFu;
  }
  __syncthreads();
  for (int t = threadIdx.x; t < n2; t += 256)
    seg[t] = sorted[t];
}

// ---------------- merged gather-mean over CSR ----------------
// node space: [0,NSTAY) s2s from hs | [NSTAY,2*NSTAY) d2s from hd | [2*NSTAY,+NDIAG) s2d from hs
__global__ __launch_bounds__(256) void k_gather3(
    const unsigned short* __restrict__ hs, const unsigned short* __restrict__ hd,
    const unsigned int* __restrict__ srt,
    const int* __restrict__ off2, const int* __restrict__ deg2, unsigned short* __restrict__ agg2,
    const int* __restrict__ off1, const int* __restrict__ deg1, unsigned short* __restrict__ agg1,
    const int* __restrict__ offD, const int* __restrict__ degD, unsigned short* __restrict__ aggD,
    int ntot) {
  const int lane = threadIdx.x & 63;
  const int grp  = lane >> 4;          // 0..3
  const int fl   = lane & 15;          // feature quad
  int gw = (blockIdx.x * 256 + threadIdx.x) >> 6;
  const int nw = (gridDim.x * 256) >> 6;
  for (int gn = gw; gn < ntot; gn += nw) {
    const unsigned short* h; const int* off; const int* deg; unsigned short* agg; int node;
    if (gn < NSTAY)            { h = hs; off = off2; deg = deg2; agg = agg2; node = gn; }
    else if (gn < 2 * NSTAY)   { h = hd; off = off1; deg = deg1; agg = agg1; node = gn - NSTAY; }
    else                       { h = hs; off = offD; deg = degD; agg = aggD; node = gn - 2 * NSTAY; }
    const int e = deg[node];
    const unsigned int* row = srt + off[node];
    float ax = 0, ay = 0, az = 0, aw = 0;
    float bx = 0, by = 0, bz = 0, bw = 0;
    int j = 0;
    for (; j + 8 <= e; j += 8) {
      unsigned int i0 = row[j + grp];
      unsigned int i1 = row[j + grp + 4];
      ushort4 v0 = *(const ushort4*)(h + (size_t)i0 * 64 + fl * 4);
      ushort4 v1 = *(const ushort4*)(h + (size_t)i1 * 64 + fl * 4);
      ax += b2f(v0.x); ay += b2f(v0.y); az += b2f(v0.z); aw += b2f(v0.w);
      bx += b2f(v1.x); by += b2f(v1.y); bz += b2f(v1.z); bw += b2f(v1.w);
    }
    if (j + grp < e) {
      unsigned int i0 = row[j + grp];
      ushort4 v0 = *(const ushort4*)(h + (size_t)i0 * 64 + fl * 4);
      ax += b2f(v0.x); ay += b2f(v0.y); az += b2f(v0.z); aw += b2f(v0.w);
    }
    if (j + grp + 4 < e) {
      unsigned int i1 = row[j + grp + 4];
      ushort4 v1 = *(const ushort4*)(h + (size_t)i1 * 64 + fl * 4);
      bx += b2f(v1.x); by += b2f(v1.y); bz += b2f(v1.z); bw += b2f(v1.w);
    }
    ax += bx; ay += by; az += bz; aw += bw;
    ax += __shfl_xor(ax, 16); ay += __shfl_xor(ay, 16);
    az += __shfl_xor(az, 16); aw += __shfl_xor(aw, 16);
    ax += __shfl_xor(ax, 32); ay += __shfl_xor(ay, 32);
    az += __shfl_xor(az, 32); aw += __shfl_xor(aw, 32);
    if (grp == 0) {
      float inv = (e > 0) ? 1.0f / (float)e : 1.0f;
      ushort4 o = make_ushort4(f2b(ax * inv), f2b(ay * inv), f2b(az * inv), f2b(aw * inv));
      *(ushort4*)(agg + (size_t)node * 64 + fl * 4) = o;
    }
  }
}

// ---------------- fused stay-side SAGE: two edge types + hetero-mean + relu + LN (+cls) ----------------
template<int CLS>
__global__ __launch_bounds__(256) void k_sage2(
    const unsigned short* __restrict__ agg2b,
    const unsigned short* __restrict__ agg1b,
    unsigned short* hb,
    const unsigned short* __restrict__ W2b, const float* __restrict__ bl2,
    const unsigned short* __restrict__ W1b, const float* __restrict__ bl1,
    const float* __restrict__ g, const float* __restrict__ bln, int n,
    const float* __restrict__ Wcf, const float* __restrict__ bcf,
    float* __restrict__ outp) {
  const int lane = threadIdx.x & 63;
  const int wv   = threadIdx.x >> 6;
  const int r    = lane & 15;
  const int kg   = lane >> 4;
  const int tile0 = (blockIdx.x * 4 + wv) * 16;
  if (tile0 >= n) return;
  const int node = tile0 + r;
  const bool ok = node < n;
  const size_t rowa = (size_t)node * 64 + kg * 8;
  bf16x8 A20 = {}, A21 = {}, A10 = {}, A11 = {}, H0 = {}, H1 = {};
  if (ok) {
    A20 = ldb8(agg2b + rowa); A21 = ldb8(agg2b + rowa + 32);
    A10 = ldb8(agg1b + rowa); A11 = ldb8(agg1b + rowa + 32);
    H0  = ldb8(hb + rowa);    H1  = ldb8(hb + rowa + 32);
  }
  f32x4 acc2[4], acc1[4];
  #pragma unroll
  for (int nt = 0; nt < 4; ++nt) {
    const unsigned short* wr = W2b + (nt * 16 + r) * 128 + kg * 8;
    f32x4 c = {0.f, 0.f, 0.f, 0.f};
    c = mfma16(A20, ldb8(wr), c);
    c = mfma16(A21, ldb8(wr + 32), c);
    c = mfma16(H0,  ldb8(wr + 64), c);
    c = mfma16(H1,  ldb8(wr + 96), c);
    acc2[nt] = c;
  }
  #pragma unroll
  for (int nt = 0; nt < 4; ++nt) {
    const unsigned short* wr = W1b + (nt * 16 + r) * 128 + kg * 8;
    f32x4 c = {0.f, 0.f, 0.f, 0.f};
    c = mfma16(A10, ldb8(wr), c);
    c = mfma16(A11, ldb8(wr + 32), c);
    c = mfma16(H0,  ldb8(wr + 64), c);
    c = mfma16(H1,  ldb8(wr + 96), c);
    acc1[nt] = c;
  }
  #pragma unroll
  for (int nt = 0; nt < 4; ++nt) {
    float b2 = bl2[nt * 16 + r], b1 = bl1[nt * 16 + r];
    #pragma unroll
    for (int j = 0; j < 4; ++j) { acc2[nt][j] += b2; acc1[nt][j] += b1; }
  }
  float ss2[4], ss1[4];
  #pragma unroll
  for (int j = 0; j < 4; ++j) {
    ss2[j] = acc2[0][j] * acc2[0][j] + acc2[1][j] * acc2[1][j]
           + acc2[2][j] * acc2[2][j] + acc2[3][j] * acc2[3][j];
    ss1[j] = acc1[0][j] * acc1[0][j] + acc1[1][j] * acc1[1][j]
           + acc1[2][j] * acc1[2][j] + acc1[3][j] * acc1[3][j];
  }
  #pragma unroll
  for (int off = 1; off < 16; off <<= 1) {
    #pragma unroll
    for (int j = 0; j < 4; ++j) {
      ss2[j] += __shfl_xor(ss2[j], off);
      ss1[j] += __shfl_xor(ss1[j], off);
    }
  }
  float v[4][4];
  #pragma unroll
  for (int j = 0; j < 4; ++j) {
    float ri2 = 1.0f / fmaxf(sqrtf(ss2[j]), 1e-12f);
    float ri1 = 1.0f / fmaxf(sqrtf(ss1[j]), 1e-12f);
    #pragma unroll
    for (int nt = 0; nt < 4; ++nt)
      v[nt][j] = fmaxf(0.5f * (acc2[nt][j] * ri2 + acc1[nt][j] * ri1), 0.f);
  }
  float s1[4], s2[4];
  #pragma unroll
  for (int j = 0; j < 4; ++j) {
    s1[j] = v[0][j] + v[1][j] + v[2][j] + v[3][j];
    s2[j] = v[0][j] * v[0][j] + v[1][j] * v[1][j] + v[2][j] * v[2][j] + v[3][j] * v[3][j];
  }
  #pragma unroll
  for (int off = 1; off < 16; off <<= 1) {
    #pragma unroll
    for (int j = 0; j < 4; ++j) {
      s1[j] += __shfl_xor(s1[j], off);
      s2[j] += __shfl_xor(s2[j], off);
    }
  }
  if (CLS == 0) {
    #pragma unroll
    for (int j = 0; j < 4; ++j) {
      int m = tile0 + kg * 4 + j;
      if (m >= n) continue;
      float mu  = s1[j] * (1.f / 64.f);
      float var = s2[j] * (1.f / 64.f) - mu * mu;
      float is  = 1.0f / sqrtf(var + 1e-5f);
      size_t base = (size_t)m * 64 + r;
      #pragma unroll
      for (int nt = 0; nt < 4; ++nt)
        hb[base + nt * 16] = f2b((v[nt][j] - mu) * is * g[nt * 16 + r] + bln[nt * 16 + r]);
    }
  } else {
    float wcc[3][4];
    #pragma unroll
    for (int c = 0; c < 3; ++c)
      #pragma unroll
      for (int nt = 0; nt < 4; ++nt) wcc[c][nt] = Wcf[c * 64 + nt * 16 + r];
    #pragma unroll
    for (int j = 0; j < 4; ++j) {
      int m = tile0 + kg * 4 + j;
      float mu  = s1[j] * (1.f / 64.f);
      float var = s2[j] * (1.f / 64.f) - mu * mu;
      float is  = 1.0f / sqrtf(var + 1e-5f);
      float p0 = 0.f, p1 = 0.f, p2 = 0.f;
      #pragma unroll
      for (int nt = 0; nt < 4; ++nt) {
        float hv = (v[nt][j] - mu) * is * g[nt * 16 + r] + bln[nt * 16 + r];
        p0 += hv * wcc[0][nt]; p1 += hv * wcc[1][nt]; p2 += hv * wcc[2][nt];
      }
      #pragma unroll
      for (int off = 1; off < 16; off <<= 1) {
        p0 += __shfl_xor(p0, off);
        p1 += __shfl_xor(p1, off);
        p2 += __shfl_xor(p2, off);
      }
      if (m < n && r < 3) {
        float pr = (r == 0) ? p0 : ((r == 1) ? p1 : p2);
        outp[(size_t)m * 3 + r] = pr + bcf[r];
      }
    }
  }
}

// ---------------- diag-side SAGE (single edge type) + relu + LN, in-place ----------------
__global__ __launch_bounds__(256) void k_sageD(
    const unsigned short* __restrict__ aggb,
    unsigned short* hb,
    const unsigned short* __restrict__ Wb, const float* __restrict__ bl,
    const float* __restrict__ g, const float* __restrict__ bln, int n) {
  const int lane = threadIdx.x & 63;
  const int wv   = threadIdx.x >> 6;
  const int r    = lane & 15;
  const int kg   = lane >> 4;
  const int tile0 = (blockIdx.x * 4 + wv) * 16;
  if (tile0 >= n) return;
  const int node = tile0 + r;
  const bool ok = node < n;
  const size_t rowa = (size_t)node * 64 + kg * 8;
  bf16x8 A0 = {}, A1 = {}, H0 = {}, H1 = {};
  if (ok) {
    A0 = ldb8(aggb + rowa); A1 = ldb8(aggb + rowa + 32);
    H0 = ldb8(hb + rowa);   H1 = ldb8(hb + rowa + 32);
  }
  f32x4 acc[4];
  #pragma unroll
  for (int nt = 0; nt < 4; ++nt) {
    const unsigned short* wr = Wb + (nt * 16 + r) * 128 + kg * 8;
    f32x4 c = {0.f, 0.f, 0.f, 0.f};
    c = mfma16(A0, ldb8(wr), c);
    c = mfma16(A1, ldb8(wr + 32), c);
    c = mfma16(H0, ldb8(wr + 64), c);
    c = mfma16(H1, ldb8(wr + 96), c);
    acc[nt] = c;
  }
  #pragma unroll
  for (int nt = 0; nt < 4; ++nt) {
    float bb = bl[nt * 16 + r];
    #pragma unroll
    for (int j = 0; j < 4; ++j) acc[nt][j] += bb;
  }
  float ss[4];
  #pragma unroll
  for (int j = 0; j < 4; ++j)
    ss[j] = acc[0][j] * acc[0][j] + acc[1][j] * acc[1][j]
          + acc[2][j] * acc[2][j] + acc[3][j] * acc[3][j];
  #pragma unroll
  for (int off = 1; off < 16; off <<= 1) {
    #pragma unroll
    for (int j = 0; j < 4; ++j) ss[j] += __shfl_xor(ss[j], off);
  }
  float v[4][4];
  #pragma unroll
  for (int j = 0; j < 4; ++j) {
    float ri = 1.0f / fmaxf(sqrtf(ss[j]), 1e-12f);
    #pragma unroll
    for (int nt = 0; nt < 4; ++nt) v[nt][j] = fmaxf(acc[nt][j] * ri, 0.f);
  }
  float s1[4], s2[4];
  #pragma unroll
  for (int j = 0; j < 4; ++j) {
    s1[j] = v[0][j] + v[1][j] + v[2][j] + v[3][j];
    s2[j] = v[0][j] * v[0][j] + v[1][j] * v[1][j] + v[2][j] * v[2][j] + v[3][j] * v[3][j];
  }
  #pragma unroll
  for (int off = 1; off < 16; off <<= 1) {
    #pragma unroll
    for (int j = 0; j < 4; ++j) {
      s1[j] += __shfl_xor(s1[j], off);
      s2[j] += __shfl_xor(s2[j], off);
    }
  }
  #pragma unroll
  for (int j = 0; j < 4; ++j) {
    int m = tile0 + kg * 4 + j;
    if (m >= n) continue;
    float mu  = s1[j] * (1.f / 64.f);
    float var = s2[j] * (1.f / 64.f) - mu * mu;
    float is  = 1.0f / sqrtf(var + 1e-5f);
    size_t base = (size_t)m * 64 + r;
    #pragma unroll
    for (int nt = 0; nt < 4; ++nt)
      hb[base + nt * 16] = f2b((v[nt][j] - mu) * is * g[nt * 16 + r] + bln[nt * 16 + r]);
  }
}

extern "C" void kernel_launch(void* const* d_in, const int* in_sizes, int n_in,
                              void* d_out, int out_size, void* d_ws, size_t ws_size,
                              hipStream_t stream) {
  const float* x_stay  = (const float*)d_in[0];
  const float* x_diag  = (const float*)d_in[1];
  const int*   s2d_src = (const int*)d_in[2];
  const int*   s2d_dst = (const int*)d_in[3];
  const int*   d2s_src = (const int*)d_in[4];
  const int*   d2s_dst = (const int*)d_in[5];
  const int*   s2s_src = (const int*)d_in[6];
  const int*   s2s_dst = (const int*)d_in[7];
  const float* Wp_stay = (const float*)d_in[8];
  const float* bp_stay = (const float*)d_in[9];
  const float* Wp_diag = (const float*)d_in[10];
  const float* bp_diag = (const float*)d_in[11];
  const float* Wl      = (const float*)d_in[12];
  const float* bl      = (const float*)d_in[13];
  const float* Wr      = (const float*)d_in[14];
  const float* ln_g    = (const float*)d_in[15];
  const float* ln_b    = (const float*)d_in[16];
  const float* Wc      = (const float*)d_in[17];
  const float* bc      = (const float*)d_in[18];

  // ---- workspace layout (float-slot units) ----
  float* ws = (float*)d_ws;
  unsigned short* hs_b   = (unsigned short*)(ws);             // 6.4M ush
  unsigned short* hd_b   = (unsigned short*)(ws + 3200000);   // 3.2M ush
  unsigned short* agg2_b = (unsigned short*)(ws + 4800000);   // 6.4M ush
  unsigned short* agg1_b = (unsigned short*)(ws + 8000000);   // 6.4M ush
  unsigned short* aggD_b = (unsigned short*)(ws + 11200000);  // 3.2M ush
  unsigned short* Wc6    = (unsigned short*)(ws + 12800000);  // 49152 ush
  unsigned short* Wps_b  = (unsigned short*)(ws + 12825000);  // 8192 ush
  unsigned short* Wpd_b  = (unsigned short*)(ws + 12830000);  // 4096 ush
  unsigned int* part1 = (unsigned int*)(ws + 12835000);       // 3*16*65536 = 3,145,728
  unsigned int* part2 = (unsigned int*)(ws + 15985000);       // 3*512*2400 = 3,686,400
  int* offD  = (int*)(ws + 19675000);                         // 50000
  int* off1  = offD + 50000;                                  // 100000
  int* off2  = off1 + 100000;                                 // 100000
  int* degD  = off2 + 100000;                                 // 50000
  int* deg1  = degD + 50000;                                  // 100000
  int* deg2  = deg1 + 100000;                                 // 100000
  int* gcur1 = deg2 + 100000;                                 // 48
  int* gcur2 = gcur1 + 48;                                    // 1536
  // end ≈ 20.18M slots ≈ 80.7 MB

  // ---- weight prep + gcur zeroing ----
  k_prep<<<247, 256, 0, stream>>>(Wp_stay, Wp_diag, Wl, Wr, Wps_b, Wpd_b, Wc6,
                                  gcur1, gcur2);

  // ---- CSR build: two coalesced partition rounds + per-range LDS sort (built once) ----
  k_part1<<<3072, 256, 0, stream>>>(s2d_src, s2d_dst, d2s_src, d2s_dst,
                                    s2s_src, s2s_dst, part1, gcur1);
  k_part2<<<3072, 256, 0, stream>>>(part1, gcur1, part2, gcur2);
  k_csr<<<1536, 256, 0, stream>>>(part2, gcur2, offD, degD, off1, deg1, off2, deg2);

  // ---- input projections (MFMA, f32 nt in, bf16 out) ----
  k_projM<4><<<1563, 256, 0, stream>>>(x_stay, Wps_b, bp_stay, hs_b, NSTAY);
  k_projM<2><<<782, 256, 0, stream>>>(x_diag, Wpd_b, bp_diag, hd_b, NDIAG);

  const int GS = (NSTAY / 16 + 3) / 4;   // 1563
  const int GD = (NDIAG / 16 + 3) / 4;   // 782

  // ================= layer 0 =================
  {
    const unsigned short* W0 = Wc6;
    const unsigned short* W1 = Wc6 + 8192;
    const unsigned short* W2 = Wc6 + 16384;
    const float* bl0 = bl, *bl1 = bl + 64, *bl2 = bl + 128;
    const float* g = ln_g, *b = ln_b;

    k_gather3<<<4096, 256, 0, stream>>>(hs_b, hd_b, part2,
        off2, deg2, agg2_b, off1, deg1, agg1_b, offD, degD, aggD_b,
        2 * NSTAY + NDIAG);
    k_sage2<0><<<GS, 256, 0, stream>>>(agg2_b, agg1_b, hs_b, W2, bl2, W1, bl1,
        g, b, NSTAY, nullptr, nullptr, nullptr);
    k_sageD<<<GD, 256, 0, stream>>>(aggD_b, hd_b, W0, bl0, g, b, NDIAG);
  }
  // ================= layer 1 (diag update dead: output depends only on h_stay) =================
  {
    const unsigned short* W1 = Wc6 + 8192 * 4;   // type 1, layer 1
    const unsigned short* W2 = Wc6 + 8192 * 5;   // type 2, layer 1
    const float* bl1 = bl + (3 + 1) * 64;
    const float* bl2 = bl + (3 + 2) * 64;
    const float* g = ln_g + 64, *b = ln_b + 64;

    k_gather3<<<4096, 256, 0, stream>>>(hs_b, hd_b, part2,
        off2, deg2, agg2_b, off1, deg1, agg1_b, offD, degD, aggD_b,
        2 * NSTAY);   // skip dead s2d aggregation
    k_sage2<1><<<GS, 256, 0, stream>>>(agg2_b, agg1_b, hs_b, W2, bl2, W1, bl1,
        g, b, NSTAY, Wc, bc, (float*)d_out);
  }
}

// Round 13
// 306.766 us; speedup vs baseline: 6.1175x; 1.1339x over previous
//
#include <hip/hip_runtime.h>

constexpr int NSTAY = 100000;
constexpr int NDIAG = 50000;
constexpr int NE    = 1000000;

constexpr int NB1   = 16;      // round-1 bins per type
constexpr int NB2   = 32;      // round-2 sub-bins per bin
constexpr int NR    = 512;     // ranges per type = NB1*NB2
constexpr int P1CAP = 65536;   // per-bin capacity   (mean 62500, sigma 242)
constexpr int P2CAP = 2400;    // per-range capacity (mean 1953,  sigma 44)
constexpr int BC1   = 160;     // LDS bin cap round 1
constexpr int BC2   = 128;     // LDS bin cap round 2

typedef __attribute__((ext_vector_type(8))) short bf16x8;
typedef __attribute__((ext_vector_type(4))) float f32x4;
typedef __attribute__((ext_vector_type(4))) float fvec4;
typedef __attribute__((ext_vector_type(4))) int   i32x4;

__device__ __forceinline__ float b2f(unsigned short u) {
  union { unsigned int i; float f; } v; v.i = (unsigned int)u << 16; return v.f;
}
__device__ __forceinline__ unsigned short f2b(float f) {
  union { float f; unsigned int i; } v; v.f = f;
  unsigned int r = (v.i + 0x7fffu + ((v.i >> 16) & 1u)) >> 16;   // RNE
  return (unsigned short)r;
}
__device__ __forceinline__ bf16x8 ldb8(const unsigned short* p) {
  return *reinterpret_cast<const bf16x8*>(p);
}
__device__ __forceinline__ f32x4 mfma16(bf16x8 a, bf16x8 b, f32x4 c) {
  return __builtin_amdgcn_mfma_f32_16x16x32_bf16(a, b, c, 0, 0, 0);
}

// ---------------- fused weight prep + gcur zeroing ----------------
__global__ __launch_bounds__(256) void k_prep(const float* __restrict__ Wps,
    const float* __restrict__ Wpd, const float* __restrict__ Wl,
    const float* __restrict__ Wr, unsigned short* __restrict__ Wps_b,
    unsigned short* __restrict__ Wpd_b, unsigned short* __restrict__ Wc6,
    int* __restrict__ gcur1, int* __restrict__ gcur2) {
  int i = blockIdx.x * 256 + threadIdx.x;
  if (i < 8192) {
    Wps_b[i] = f2b(Wps[i]);
  } else if (i < 12288) {
    Wpd_b[i - 8192] = f2b(Wpd[i - 8192]);
  } else if (i < 61440) {
    int t = i - 12288;
    int k = t & 127, f = (t >> 7) & 63, ty = t >> 13;
    float v = (k < 64) ? Wl[ty * 4096 + f * 64 + k] : Wr[ty * 4096 + f * 64 + (k - 64)];
    Wc6[t] = f2b(v);
  } else if (i < 61440 + 48) {
    gcur1[i - 61440] = 0;
  } else if (i < 61440 + 48 + 1536) {
    gcur2[i - 61440 - 48] = 0;
  }
}

// ---------------- MFMA input projection: out = relu(x @ Wb.T + b), K = NKC*32, x f32 (nt) ----------------
template<int NKC>
__global__ __launch_bounds__(256) void k_projM(const float* __restrict__ x,
    const unsigned short* __restrict__ Wb, const float* __restrict__ bias,
    unsigned short* __restrict__ out, int n) {
  const int lane = threadIdx.x & 63;
  const int wv   = threadIdx.x >> 6;
  const int r    = lane & 15;
  const int kg   = lane >> 4;
  const int tile0 = (blockIdx.x * 4 + wv) * 16;
  if (tile0 >= n) return;
  const int K = NKC * 32;
  bf16x8 Bf[4][NKC];
  #pragma unroll
  for (int nt = 0; nt < 4; ++nt)
    #pragma unroll
    for (int kc = 0; kc < NKC; ++kc)
      Bf[nt][kc] = ldb8(Wb + (nt * 16 + r) * K + kc * 32 + kg * 8);
  const int node = tile0 + r;
  const bool ok = node < n;
  bf16x8 Af[NKC] = {};
  if (ok) {
    #pragma unroll
    for (int kc = 0; kc < NKC; ++kc) {
      const float* px = x + (size_t)node * K + kc * 32 + kg * 8;
      fvec4 lo = __builtin_nontemporal_load(reinterpret_cast<const fvec4*>(px));
      fvec4 hi = __builtin_nontemporal_load(reinterpret_cast<const fvec4*>(px + 4));
      bf16x8 a;
      a[0] = (short)f2b(lo.x); a[1] = (short)f2b(lo.y);
      a[2] = (short)f2b(lo.z); a[3] = (short)f2b(lo.w);
      a[4] = (short)f2b(hi.x); a[5] = (short)f2b(hi.y);
      a[6] = (short)f2b(hi.z); a[7] = (short)f2b(hi.w);
      Af[kc] = a;
    }
  }
  f32x4 acc[4];
  #pragma unroll
  for (int nt = 0; nt < 4; ++nt) {
    f32x4 c = {0.f, 0.f, 0.f, 0.f};
    #pragma unroll
    for (int kc = 0; kc < NKC; ++kc)
      c = mfma16(Af[kc], Bf[nt][kc], c);
    acc[nt] = c;
  }
  #pragma unroll
  for (int j = 0; j < 4; ++j) {
    int m = tile0 + kg * 4 + j;
    if (m < n) {
      size_t base = (size_t)m * 64 + r;
      #pragma unroll
      for (int nt = 0; nt < 4; ++nt)
        out[base + nt * 16] = f2b(fmaxf(acc[nt][j] + bias[nt * 16 + r], 0.f));
    }
  }
}

// ---------------- partition round 1: 16 bins per type (LDS int atomics + coalesced flush) ----------------
__global__ __launch_bounds__(256) void k_part1(
    const int* __restrict__ s0, const int* __restrict__ d0,
    const int* __restrict__ s1, const int* __restrict__ d1,
    const int* __restrict__ s2, const int* __restrict__ d2,
    unsigned int* __restrict__ part1, int* __restrict__ gcur1) {
  __shared__ unsigned int buf[NB1][BC1];
  __shared__ int bcnt[NB1];
  __shared__ int bbase[NB1];
  const int ty = blockIdx.x >> 10;
  const int bx = blockIdx.x & 1023;
  const int* src; const int* dst; int cpc1;
  if (ty == 0)      { src = s0; dst = d0; cpc1 = (NDIAG + NB1 - 1) / NB1; }
  else if (ty == 1) { src = s1; dst = d1; cpc1 = (NSTAY + NB1 - 1) / NB1; }
  else              { src = s2; dst = d2; cpc1 = (NSTAY + NB1 - 1) / NB1; }
  if (threadIdx.x < NB1) bcnt[threadIdx.x] = 0;
  __syncthreads();
  const int NE4 = NE / 4;
  int i = bx * 256 + threadIdx.x;
  if (i < NE4) {
    i32x4 dd = __builtin_nontemporal_load(reinterpret_cast<const i32x4*>(dst) + i);
    i32x4 ss = __builtin_nontemporal_load(reinterpret_cast<const i32x4*>(src) + i);
    #pragma unroll
    for (int u = 0; u < 4; ++u) {
      int d = dd[u];
      int b = d / cpc1;
      unsigned int pk = ((unsigned int)(d - b * cpc1) << 17) | (unsigned int)ss[u];
      int p = atomicAdd(&bcnt[b], 1);
      if (p < BC1) buf[b][p] = pk;
    }
  }
  __syncthreads();
  if (threadIdx.x < NB1) {
    int c = bcnt[threadIdx.x]; if (c > BC1) c = BC1;
    bcnt[threadIdx.x] = c;
    bbase[threadIdx.x] = atomicAdd(&gcur1[ty * NB1 + threadIdx.x], c);
  }
  __syncthreads();
  #pragma unroll
  for (int b = 0; b < NB1; ++b) {
    int c = bcnt[b], base = bbase[b];
    if (base > P1CAP - c) { int room = P1CAP - base; c = room > 0 ? room : 0; }
    unsigned int* op = part1 + ((size_t)ty * NB1 + b) * P1CAP + base;
    for (int t = threadIdx.x; t < c; t += 256)
      op[t] = buf[b][t];
  }
}

// ---------------- partition round 2: each bin -> 32 sub-bins (512 ranges/type) ----------------
__global__ __launch_bounds__(256) void k_part2(
    const unsigned int* __restrict__ part1, const int* __restrict__ gcur1,
    unsigned int* __restrict__ part2, int* __restrict__ gcur2) {
  __shared__ unsigned int buf[NB2][BC2];
  __shared__ int bcnt[NB2];
  __shared__ int bbase[NB2];
  const int gid = blockIdx.x;
  const int ty  = gid >> 10;
  const int bin = (gid >> 6) & 15;
  const int sub = gid & 63;
  const int cpc2 = (ty == 0) ? 98 : 196;
  int n1 = gcur1[ty * NB1 + bin]; if (n1 > P1CAP) n1 = P1CAP;
  const unsigned int* seg = part1 + ((size_t)ty * NB1 + bin) * P1CAP;
  if (threadIdx.x < NB2) bcnt[threadIdx.x] = 0;
  __syncthreads();
  int i4 = sub * 256 + threadIdx.x;
  int i0 = i4 * 4;
  if (i0 + 4 <= n1) {
    i32x4 vv = *reinterpret_cast<const i32x4*>(seg + i0);
    #pragma unroll
    for (int u = 0; u < 4; ++u) {
      unsigned int v = (unsigned int)vv[u];
      int dcl = (int)(v >> 17);
      int sb = dcl / cpc2;
      unsigned int pk = ((unsigned int)(dcl - sb * cpc2) << 17) | (v & 0x1FFFFu);
      int p = atomicAdd(&bcnt[sb], 1);
      if (p < BC2) buf[sb][p] = pk;
    }
  } else {
    for (int u = 0; u < 4; ++u) {
      int idx = i0 + u;
      if (idx < n1) {
        unsigned int v = seg[idx];
        int dcl = (int)(v >> 17);
        int sb = dcl / cpc2;
        unsigned int pk = ((unsigned int)(dcl - sb * cpc2) << 17) | (v & 0x1FFFFu);
        int p = atomicAdd(&bcnt[sb], 1);
        if (p < BC2) buf[sb][p] = pk;
      }
    }
  }
  __syncthreads();
  if (threadIdx.x < NB2) {
    int c = bcnt[threadIdx.x]; if (c > BC2) c = BC2;
    bcnt[threadIdx.x] = c;
    bbase[threadIdx.x] = atomicAdd(&gcur2[ty * NR + bin * NB2 + threadIdx.x], c);
  }
  __syncthreads();
  #pragma unroll
  for (int b = 0; b < NB2; ++b) {
    int c = bcnt[b], base = bbase[b];
    if (base > P2CAP - c) { int room = P2CAP - base; c = room > 0 ? room : 0; }
    unsigned int* op = part2 + ((size_t)ty * NR + bin * NB2 + b) * P2CAP + base;
    for (int t = threadIdx.x; t < c; t += 256)
      op[t] = buf[b][t];
  }
}

// ---------------- CSR build per range: count (int LDS atomics) -> scan -> sort in LDS -> coalesced flush ----------------
__global__ __launch_bounds__(256) void k_csr(
    unsigned int* __restrict__ part2, const int* __restrict__ gcur2,
    int* __restrict__ offD, int* __restrict__ degD,
    int* __restrict__ off1, int* __restrict__ deg1,
    int* __restrict__ off2, int* __restrict__ deg2) {
  __shared__ int cnt[196];
  __shared__ int cur[196];
  __shared__ unsigned int sorted[P2CAP];
  const int ty = blockIdx.x >> 9;
  const int r  = blockIdx.x & (NR - 1);
  int cpc1, cpc2, nnode; int* off; int* deg;
  if (ty == 0)      { cpc1 = 3125; cpc2 = 98;  nnode = NDIAG; off = offD; deg = degD; }
  else if (ty == 1) { cpc1 = 6250; cpc2 = 196; nnode = NSTAY; off = off1; deg = deg1; }
  else              { cpc1 = 6250; cpc2 = 196; nnode = NSTAY; off = off2; deg = deg2; }
  const int rid = ty * NR + r;
  int n2 = gcur2[rid]; if (n2 > P2CAP) n2 = P2CAP;
  unsigned int* seg = part2 + (size_t)rid * P2CAP;
  for (int i = threadIdx.x; i < cpc2; i += 256) cnt[i] = 0;
  __syncthreads();
  for (int t = threadIdx.x; t < n2; t += 256)
    atomicAdd(&cnt[seg[t] >> 17], 1);
  __syncthreads();
  if (threadIdx.x < 64) {
    int lane = threadIdx.x;
    int c0 = (lane * 4     < cpc2) ? cnt[lane * 4]     : 0;
    int c1 = (lane * 4 + 1 < cpc2) ? cnt[lane * 4 + 1] : 0;
    int c2 = (lane * 4 + 2 < cpc2) ? cnt[lane * 4 + 2] : 0;
    int c3 = (lane * 4 + 3 < cpc2) ? cnt[lane * 4 + 3] : 0;
    int qs = c0 + c1 + c2 + c3;
    int x = qs;
    #pragma unroll
    for (int o = 1; o < 64; o <<= 1) { int y = __shfl_up(x, o); if (lane >= o) x += y; }
    int base = x - qs;
    if (lane * 4     < cpc2) cur[lane * 4]     = base;
    if (lane * 4 + 1 < cpc2) cur[lane * 4 + 1] = base + c0;
    if (lane * 4 + 2 < cpc2) cur[lane * 4 + 2] = base + c0 + c1;
    if (lane * 4 + 3 < cpc2) cur[lane * 4 + 3] = base + c0 + c1 + c2;
  }
  __syncthreads();
  const int bin = r >> 5, sb = r & 31;
  const int node0 = bin * cpc1 + sb * cpc2;
  int dmax = cpc1 - sb * cpc2; if (dmax > cpc2) dmax = cpc2;
  for (int i = threadIdx.x; i < cpc2; i += 256) {
    int node = node0 + i;
    if (i < dmax && node < nnode) {
      off[node] = rid * P2CAP + cur[i];
      deg[node] = cnt[i];
    }
  }
  __syncthreads();
  for (int t = threadIdx.x; t < n2; t += 256) {
    unsigned int v = seg[t];
    int pos = atomicAdd(&cur[v >> 17], 1);
    sorted[pos] = v & 0x1FFFFu;
  }
  __syncthreads();
  for (int t = threadIdx.x; t < n2; t += 256)
    seg[t] = sorted[t];
}

// ---------------- merged gather-mean over CSR: one 16-lane group per node, 4-deep MLP ----------------
// node space: [0,NSTAY) s2s from hs | [NSTAY,2*NSTAY) d2s from hd | [2*NSTAY,+NDIAG) s2d from hs
__global__ __launch_bounds__(256) void k_gather3(
    const unsigned short* __restrict__ hs, const unsigned short* __restrict__ hd,
    const unsigned int* __restrict__ srt,
    const int* __restrict__ off2, const int* __restrict__ deg2, unsigned short* __restrict__ agg2,
    const int* __restrict__ off1, const int* __restrict__ deg1, unsigned short* __restrict__ agg1,
    const int* __restrict__ offD, const int* __restrict__ degD, unsigned short* __restrict__ aggD,
    int ntot) {
  const int fl = threadIdx.x & 15;                 // feature quad within group
  int gg = (blockIdx.x * 256 + threadIdx.x) >> 4;  // global 16-lane group = one node
  const int ng = (gridDim.x * 256) >> 4;
  for (int gn = gg; gn < ntot; gn += ng) {
    const unsigned short* h; const int* off; const int* deg; unsigned short* agg; int node;
    if (gn < NSTAY)            { h = hs; off = off2; deg = deg2; agg = agg2; node = gn; }
    else if (gn < 2 * NSTAY)   { h = hd; off = off1; deg = deg1; agg = agg1; node = gn - NSTAY; }
    else                       { h = hs; off = offD; deg = degD; agg = aggD; node = gn - 2 * NSTAY; }
    const int e = deg[node];
    const unsigned int* row = srt + off[node];
    float a0x = 0, a0y = 0, a0z = 0, a0w = 0;
    float a1x = 0, a1y = 0, a1z = 0, a1w = 0;
    float a2x = 0, a2y = 0, a2z = 0, a2w = 0;
    float a3x = 0, a3y = 0, a3z = 0, a3w = 0;
    int j = 0;
    for (; j + 4 <= e; j += 4) {
      unsigned int i0 = row[j], i1 = row[j + 1], i2 = row[j + 2], i3 = row[j + 3];
      ushort4 v0 = *(const ushort4*)(h + (size_t)i0 * 64 + fl * 4);
      ushort4 v1 = *(const ushort4*)(h + (size_t)i1 * 64 + fl * 4);
      ushort4 v2 = *(const ushort4*)(h + (size_t)i2 * 64 + fl * 4);
      ushort4 v3 = *(const ushort4*)(h + (size_t)i3 * 64 + fl * 4);
      a0x += b2f(v0.x); a0y += b2f(v0.y); a0z += b2f(v0.z); a0w += b2f(v0.w);
      a1x += b2f(v1.x); a1y += b2f(v1.y); a1z += b2f(v1.z); a1w += b2f(v1.w);
      a2x += b2f(v2.x); a2y += b2f(v2.y); a2z += b2f(v2.z); a2w += b2f(v2.w);
      a3x += b2f(v3.x); a3y += b2f(v3.y); a3z += b2f(v3.z); a3w += b2f(v3.w);
    }
    for (; j < e; ++j) {
      unsigned int i0 = row[j];
      ushort4 v0 = *(const ushort4*)(h + (size_t)i0 * 64 + fl * 4);
      a0x += b2f(v0.x); a0y += b2f(v0.y); a0z += b2f(v0.z); a0w += b2f(v0.w);
    }
    float ax = (a0x + a1x) + (a2x + a3x);
    float ay = (a0y + a1y) + (a2y + a3y);
    float az = (a0z + a1z) + (a2z + a3z);
    float aw = (a0w + a1w) + (a2w + a3w);
    float inv = (e > 0) ? 1.0f / (float)e : 1.0f;
    ushort4 o = make_ushort4(f2b(ax * inv), f2b(ay * inv), f2b(az * inv), f2b(aw * inv));
    *(ushort4*)(agg + (size_t)node * 64 + fl * 4) = o;
  }
}

// ---------------- fused stay-side SAGE: two edge types + hetero-mean + relu + LN (+cls) ----------------
template<int CLS>
__global__ __launch_bounds__(256) void k_sage2(
    const unsigned short* __restrict__ agg2b,
    const unsigned short* __restrict__ agg1b,
    unsigned short* hb,
    const unsigned short* __restrict__ W2b, const float* __restrict__ bl2,
    const unsigned short* __restrict__ W1b, const float* __restrict__ bl1,
    const float* __restrict__ g, const float* __restrict__ bln, int n,
    const float* __restrict__ Wcf, const float* __restrict__ bcf,
    float* __restrict__ outp) {
  const int lane = threadIdx.x & 63;
  const int wv   = threadIdx.x >> 6;
  const int r    = lane & 15;
  const int kg   = lane >> 4;
  const int tile0 = (blockIdx.x * 4 + wv) * 16;
  if (tile0 >= n) return;
  const int node = tile0 + r;
  const bool ok = node < n;
  const size_t rowa = (size_t)node * 64 + kg * 8;
  bf16x8 A20 = {}, A21 = {}, A10 = {}, A11 = {}, H0 = {}, H1 = {};
  if (ok) {
    A20 = ldb8(agg2b + rowa); A21 = ldb8(agg2b + rowa + 32);
    A10 = ldb8(agg1b + rowa); A11 = ldb8(agg1b + rowa + 32);
    H0  = ldb8(hb + rowa);    H1  = ldb8(hb + rowa + 32);
  }
  f32x4 acc2[4], acc1[4];
  #pragma unroll
  for (int nt = 0; nt < 4; ++nt) {
    const unsigned short* wr = W2b + (nt * 16 + r) * 128 + kg * 8;
    f32x4 c = {0.f, 0.f, 0.f, 0.f};
    c = mfma16(A20, ldb8(wr), c);
    c = mfma16(A21, ldb8(wr + 32), c);
    c = mfma16(H0,  ldb8(wr + 64), c);
    c = mfma16(H1,  ldb8(wr + 96), c);
    acc2[nt] = c;
  }
  #pragma unroll
  for (int nt = 0; nt < 4; ++nt) {
    const unsigned short* wr = W1b + (nt * 16 + r) * 128 + kg * 8;
    f32x4 c = {0.f, 0.f, 0.f, 0.f};
    c = mfma16(A10, ldb8(wr), c);
    c = mfma16(A11, ldb8(wr + 32), c);
    c = mfma16(H0,  ldb8(wr + 64), c);
    c = mfma16(H1,  ldb8(wr + 96), c);
    acc1[nt] = c;
  }
  #pragma unroll
  for (int nt = 0; nt < 4; ++nt) {
    float b2 = bl2[nt * 16 + r], b1 = bl1[nt * 16 + r];
    #pragma unroll
    for (int j = 0; j < 4; ++j) { acc2[nt][j] += b2; acc1[nt][j] += b1; }
  }
  float ss2[4], ss1[4];
  #pragma unroll
  for (int j = 0; j < 4; ++j) {
    ss2[j] = acc2[0][j] * acc2[0][j] + acc2[1][j] * acc2[1][j]
           + acc2[2][j] * acc2[2][j] + acc2[3][j] * acc2[3][j];
    ss1[j] = acc1[0][j] * acc1[0][j] + acc1[1][j] * acc1[1][j]
           + acc1[2][j] * acc1[2][j] + acc1[3][j] * acc1[3][j];
  }
  #pragma unroll
  for (int off = 1; off < 16; off <<= 1) {
    #pragma unroll
    for (int j = 0; j < 4; ++j) {
      ss2[j] += __shfl_xor(ss2[j], off);
      ss1[j] += __shfl_xor(ss1[j], off);
    }
  }
  float v[4][4];
  #pragma unroll
  for (int j = 0; j < 4; ++j) {
    float ri2 = 1.0f / fmaxf(sqrtf(ss2[j]), 1e-12f);
    float ri1 = 1.0f / fmaxf(sqrtf(ss1[j]), 1e-12f);
    #pragma unroll
    for (int nt = 0; nt < 4; ++nt)
      v[nt][j] = fmaxf(0.5f * (acc2[nt][j] * ri2 + acc1[nt][j] * ri1), 0.f);
  }
  float s1[4], s2[4];
  #pragma unroll
  for (int j = 0; j < 4; ++j) {
    s1[j] = v[0][j] + v[1][j] + v[2][j] + v[3][j];
    s2[j] = v[0][j] * v[0][j] + v[1][j] * v[1][j] + v[2][j] * v[2][j] + v[3][j] * v[3][j];
  }
  #pragma unroll
  for (int off = 1; off < 16; off <<= 1) {
    #pragma unroll
    for (int j = 0; j < 4; ++j) {
      s1[j] += __shfl_xor(s1[j], off);
      s2[j] += __shfl_xor(s2[j], off);
    }
  }
  if (CLS == 0) {
    #pragma unroll
    for (int j = 0; j < 4; ++j) {
      int m = tile0 + kg * 4 + j;
      if (m >= n) continue;
      float mu  = s1[j] * (1.f / 64.f);
      float var = s2[j] * (1.f / 64.f) - mu * mu;
      float is  = 1.0f / sqrtf(var + 1e-5f);
      size_t base = (size_t)m * 64 + r;
      #pragma unroll
      for (int nt = 0; nt < 4; ++nt)
        hb[base + nt * 16] = f2b((v[nt][j] - mu) * is * g[nt * 16 + r] + bln[nt * 16 + r]);
    }
  } else {
    float wcc[3][4];
    #pragma unroll
    for (int c = 0; c < 3; ++c)
      #pragma unroll
      for (int nt = 0; nt < 4; ++nt) wcc[c][nt] = Wcf[c * 64 + nt * 16 + r];
    #pragma unroll
    for (int j = 0; j < 4; ++j) {
      int m = tile0 + kg * 4 + j;
      float mu  = s1[j] * (1.f / 64.f);
      float var = s2[j] * (1.f / 64.f) - mu * mu;
      float is  = 1.0f / sqrtf(var + 1e-5f);
      float p0 = 0.f, p1 = 0.f, p2 = 0.f;
      #pragma unroll
      for (int nt = 0; nt < 4; ++nt) {
        float hv = (v[nt][j] - mu) * is * g[nt * 16 + r] + bln[nt * 16 + r];
        p0 += hv * wcc[0][nt]; p1 += hv * wcc[1][nt]; p2 += hv * wcc[2][nt];
      }
      #pragma unroll
      for (int off = 1; off < 16; off <<= 1) {
        p0 += __shfl_xor(p0, off);
        p1 += __shfl_xor(p1, off);
        p2 += __shfl_xor(p2, off);
      }
      if (m < n && r < 3) {
        float pr = (r == 0) ? p0 : ((r == 1) ? p1 : p2);
        outp[(size_t)m * 3 + r] = pr + bcf[r];
      }
    }
  }
}

// ---------------- diag-side SAGE (single edge type) + relu + LN, in-place ----------------
__global__ __launch_bounds__(256) void k_sageD(
    const unsigned short* __restrict__ aggb,
    unsigned short* hb,
    const unsigned short* __restrict__ Wb, const float* __restrict__ bl,
    const float* __restrict__ g, const float* __restrict__ bln, int n) {
  const int lane = threadIdx.x & 63;
  const int wv   = threadIdx.x >> 6;
  const int r    = lane & 15;
  const int kg   = lane >> 4;
  const int tile0 = (blockIdx.x * 4 + wv) * 16;
  if (tile0 >= n) return;
  const int node = tile0 + r;
  const bool ok = node < n;
  const size_t rowa = (size_t)node * 64 + kg * 8;
  bf16x8 A0 = {}, A1 = {}, H0 = {}, H1 = {};
  if (ok) {
    A0 = ldb8(aggb + rowa); A1 = ldb8(aggb + rowa + 32);
    H0 = ldb8(hb + rowa);   H1 = ldb8(hb + rowa + 32);
  }
  f32x4 acc[4];
  #pragma unroll
  for (int nt = 0; nt < 4; ++nt) {
    const unsigned short* wr = Wb + (nt * 16 + r) * 128 + kg * 8;
    f32x4 c = {0.f, 0.f, 0.f, 0.f};
    c = mfma16(A0, ldb8(wr), c);
    c = mfma16(A1, ldb8(wr + 32), c);
    c = mfma16(H0, ldb8(wr + 64), c);
    c = mfma16(H1, ldb8(wr + 96), c);
    acc[nt] = c;
  }
  #pragma unroll
  for (int nt = 0; nt < 4; ++nt) {
    float bb = bl[nt * 16 + r];
    #pragma unroll
    for (int j = 0; j < 4; ++j) acc[nt][j] += bb;
  }
  float ss[4];
  #pragma unroll
  for (int j = 0; j < 4; ++j)
    ss[j] = acc[0][j] * acc[0][j] + acc[1][j] * acc[1][j]
          + acc[2][j] * acc[2][j] + acc[3][j] * acc[3][j];
  #pragma unroll
  for (int off = 1; off < 16; off <<= 1) {
    #pragma unroll
    for (int j = 0; j < 4; ++j) ss[j] += __shfl_xor(ss[j], off);
  }
  float v[4][4];
  #pragma unroll
  for (int j = 0; j < 4; ++j) {
    float ri = 1.0f / fmaxf(sqrtf(ss[j]), 1e-12f);
    #pragma unroll
    for (int nt = 0; nt < 4; ++nt) v[nt][j] = fmaxf(acc[nt][j] * ri, 0.f);
  }
  float s1[4], s2[4];
  #pragma unroll
  for (int j = 0; j < 4; ++j) {
    s1[j] = v[0][j] + v[1][j] + v[2][j] + v[3][j];
    s2[j] = v[0][j] * v[0][j] + v[1][j] * v[1][j] + v[2][j] * v[2][j] + v[3][j] * v[3][j];
  }
  #pragma unroll
  for (int off = 1; off < 16; off <<= 1) {
    #pragma unroll
    for (int j = 0; j < 4; ++j) {
      s1[j] += __shfl_xor(s1[j], off);
      s2[j] += __shfl_xor(s2[j], off);
    }
  }
  #pragma unroll
  for (int j = 0; j < 4; ++j) {
    int m = tile0 + kg * 4 + j;
    if (m >= n) continue;
    float mu  = s1[j] * (1.f / 64.f);
    float var = s2[j] * (1.f / 64.f) - mu * mu;
    float is  = 1.0f / sqrtf(var + 1e-5f);
    size_t base = (size_t)m * 64 + r;
    #pragma unroll
    for (int nt = 0; nt < 4; ++nt)
      hb[base + nt * 16] = f2b((v[nt][j] - mu) * is * g[nt * 16 + r] + bln[nt * 16 + r]);
  }
}

extern "C" void kernel_launch(void* const* d_in, const int* in_sizes, int n_in,
                              void* d_out, int out_size, void* d_ws, size_t ws_size,
                              hipStream_t stream) {
  const float* x_stay  = (const float*)d_in[0];
  const float* x_diag  = (const float*)d_in[1];
  const int*   s2d_src = (const int*)d_in[2];
  const int*   s2d_dst = (const int*)d_in[3];
  const int*   d2s_src = (const int*)d_in[4];
  const int*   d2s_dst = (const int*)d_in[5];
  const int*   s2s_src = (const int*)d_in[6];
  const int*   s2s_dst = (const int*)d_in[7];
  const float* Wp_stay = (const float*)d_in[8];
  const float* bp_stay = (const float*)d_in[9];
  const float* Wp_diag = (const float*)d_in[10];
  const float* bp_diag = (const float*)d_in[11];
  const float* Wl      = (const float*)d_in[12];
  const float* bl      = (const float*)d_in[13];
  const float* Wr      = (const float*)d_in[14];
  const float* ln_g    = (const float*)d_in[15];
  const float* ln_b    = (const float*)d_in[16];
  const float* Wc      = (const float*)d_in[17];
  const float* bc      = (const float*)d_in[18];

  // ---- workspace layout (float-slot units) ----
  float* ws = (float*)d_ws;
  unsigned short* hs_b   = (unsigned short*)(ws);             // 6.4M ush
  unsigned short* hd_b   = (unsigned short*)(ws + 3200000);   // 3.2M ush
  unsigned short* agg2_b = (unsigned short*)(ws + 4800000);   // 6.4M ush
  unsigned short* agg1_b = (unsigned short*)(ws + 8000000);   // 6.4M ush
  unsigned short* aggD_b = (unsigned short*)(ws + 11200000);  // 3.2M ush
  unsigned short* Wc6    = (unsigned short*)(ws + 12800000);  // 49152 ush
  unsigned short* Wps_b  = (unsigned short*)(ws + 12825000);  // 8192 ush
  unsigned short* Wpd_b  = (unsigned short*)(ws + 12830000);  // 4096 ush
  unsigned int* part1 = (unsigned int*)(ws + 12835000);       // 3*16*65536 = 3,145,728
  unsigned int* part2 = (unsigned int*)(ws + 15985000);       // 3*512*2400 = 3,686,400
  int* offD  = (int*)(ws + 19675000);                         // 50000
  int* off1  = offD + 50000;                                  // 100000
  int* off2  = off1 + 100000;                                 // 100000
  int* degD  = off2 + 100000;                                 // 50000
  int* deg1  = degD + 50000;                                  // 100000
  int* deg2  = deg1 + 100000;                                 // 100000
  int* gcur1 = deg2 + 100000;                                 // 48
  int* gcur2 = gcur1 + 48;                                    // 1536
  // end ≈ 20.18M slots ≈ 80.7 MB

  // ---- weight prep + gcur zeroing ----
  k_prep<<<247, 256, 0, stream>>>(Wp_stay, Wp_diag, Wl, Wr, Wps_b, Wpd_b, Wc6,
                                  gcur1, gcur2);

  // ---- CSR build: two coalesced partition rounds + per-range LDS sort (built once) ----
  k_part1<<<3072, 256, 0, stream>>>(s2d_src, s2d_dst, d2s_src, d2s_dst,
                                    s2s_src, s2s_dst, part1, gcur1);
  k_part2<<<3072, 256, 0, stream>>>(part1, gcur1, part2, gcur2);
  k_csr<<<1536, 256, 0, stream>>>(part2, gcur2, offD, degD, off1, deg1, off2, deg2);

  // ---- input projections (MFMA, f32 nt in, bf16 out) ----
  k_projM<4><<<1563, 256, 0, stream>>>(x_stay, Wps_b, bp_stay, hs_b, NSTAY);
  k_projM<2><<<782, 256, 0, stream>>>(x_diag, Wpd_b, bp_diag, hd_b, NDIAG);

  const int GS = (NSTAY / 16 + 3) / 4;   // 1563
  const int GD = (NDIAG / 16 + 3) / 4;   // 782

  // ================= layer 0 =================
  {
    const unsigned short* W0 = Wc6;
    const unsigned short* W1 = Wc6 + 8192;
    const unsigned short* W2 = Wc6 + 16384;
    const float* bl0 = bl, *bl1 = bl + 64, *bl2 = bl + 128;
    const float* g = ln_g, *b = ln_b;

    k_gather3<<<4096, 256, 0, stream>>>(hs_b, hd_b, part2,
        off2, deg2, agg2_b, off1, deg1, agg1_b, offD, degD, aggD_b,
        2 * NSTAY + NDIAG);
    k_sage2<0><<<GS, 256, 0, stream>>>(agg2_b, agg1_b, hs_b, W2, bl2, W1, bl1,
        g, b, NSTAY, nullptr, nullptr, nullptr);
    k_sageD<<<GD, 256, 0, stream>>>(aggD_b, hd_b, W0, bl0, g, b, NDIAG);
  }
  // ================= layer 1 (diag update dead: output depends only on h_stay) =================
  {
    const unsigned short* W1 = Wc6 + 8192 * 4;   // type 1, layer 1
    const unsigned short* W2 = Wc6 + 8192 * 5;   // type 2, layer 1
    const float* bl1 = bl + (3 + 1) * 64;
    const float* bl2 = bl + (3 + 2) * 64;
    const float* g = ln_g + 64, *b = ln_b + 64;

    k_gather3<<<4096, 256, 0, stream>>>(hs_b, hd_b, part2,
        off2, deg2, agg2_b, off1, deg1, agg1_b, offD, degD, aggD_b,
        2 * NSTAY);   // skip dead s2d aggregation
    k_sage2<1><<<GS, 256, 0, stream>>>(agg2_b, agg1_b, hs_b, W2, bl2, W1, bl1,
        g, b, NSTAY, Wc, bc, (float*)d_out);
  }
}

// Round 14
// 283.870 us; speedup vs baseline: 6.6110x; 1.0807x over previous
//
#include <hip/hip_runtime.h>

constexpr int NSTAY = 100000;
constexpr int NDIAG = 50000;
constexpr int NE    = 1000000;

constexpr int NB1   = 16;      // round-1 bins per type
constexpr int NB2   = 32;      // round-2 sub-bins per bin
constexpr int NR    = 512;     // ranges per type = NB1*NB2
constexpr int P1CAP = 65536;   // per-bin capacity   (mean 62500, sigma 242)
constexpr int P2CAP = 2400;    // per-range capacity (mean 1953,  sigma 44)
constexpr int BC1   = 160;     // LDS bin cap round 1
constexpr int BC2   = 128;     // LDS bin cap round 2

typedef __attribute__((ext_vector_type(8))) short bf16x8;
typedef __attribute__((ext_vector_type(4))) float f32x4;
typedef __attribute__((ext_vector_type(4))) float fvec4;
typedef __attribute__((ext_vector_type(4))) int   i32x4;

__device__ __forceinline__ float b2f(unsigned short u) {
  union { unsigned int i; float f; } v; v.i = (unsigned int)u << 16; return v.f;
}
__device__ __forceinline__ unsigned short f2b(float f) {
  union { float f; unsigned int i; } v; v.f = f;
  unsigned int r = (v.i + 0x7fffu + ((v.i >> 16) & 1u)) >> 16;   // RNE
  return (unsigned short)r;
}
__device__ __forceinline__ bf16x8 ldb8(const unsigned short* p) {
  return *reinterpret_cast<const bf16x8*>(p);
}
__device__ __forceinline__ f32x4 mfma16(bf16x8 a, bf16x8 b, f32x4 c) {
  return __builtin_amdgcn_mfma_f32_16x16x32_bf16(a, b, c, 0, 0, 0);
}

// ---------------- fused weight prep + gcur zeroing ----------------
__global__ __launch_bounds__(256) void k_prep(const float* __restrict__ Wps,
    const float* __restrict__ Wpd, const float* __restrict__ Wl,
    const float* __restrict__ Wr, unsigned short* __restrict__ Wps_b,
    unsigned short* __restrict__ Wpd_b, unsigned short* __restrict__ Wc6,
    int* __restrict__ gcur1, int* __restrict__ gcur2) {
  int i = blockIdx.x * 256 + threadIdx.x;
  if (i < 8192) {
    Wps_b[i] = f2b(Wps[i]);
  } else if (i < 12288) {
    Wpd_b[i - 8192] = f2b(Wpd[i - 8192]);
  } else if (i < 61440) {
    int t = i - 12288;
    int k = t & 127, f = (t >> 7) & 63, ty = t >> 13;
    float v = (k < 64) ? Wl[ty * 4096 + f * 64 + k] : Wr[ty * 4096 + f * 64 + (k - 64)];
    Wc6[t] = f2b(v);
  } else if (i < 61440 + 48) {
    gcur1[i - 61440] = 0;
  } else if (i < 61440 + 48 + 1536) {
    gcur2[i - 61440 - 48] = 0;
  }
}

// ---------------- MFMA input projection (device body) ----------------
template<int NKC>
__device__ __forceinline__ void projM_body(int blk, const float* __restrict__ x,
    const unsigned short* __restrict__ Wb, const float* __restrict__ bias,
    unsigned short* __restrict__ out, int n) {
  const int lane = threadIdx.x & 63;
  const int wv   = threadIdx.x >> 6;
  const int r    = lane & 15;
  const int kg   = lane >> 4;
  const int tile0 = (blk * 4 + wv) * 16;
  if (tile0 >= n) return;
  const int K = NKC * 32;
  bf16x8 Bf[4][NKC];
  #pragma unroll
  for (int nt = 0; nt < 4; ++nt)
    #pragma unroll
    for (int kc = 0; kc < NKC; ++kc)
      Bf[nt][kc] = ldb8(Wb + (nt * 16 + r) * K + kc * 32 + kg * 8);
  const int node = tile0 + r;
  const bool ok = node < n;
  bf16x8 Af[NKC] = {};
  if (ok) {
    #pragma unroll
    for (int kc = 0; kc < NKC; ++kc) {
      const float* px = x + (size_t)node * K + kc * 32 + kg * 8;
      fvec4 lo = __builtin_nontemporal_load(reinterpret_cast<const fvec4*>(px));
      fvec4 hi = __builtin_nontemporal_load(reinterpret_cast<const fvec4*>(px + 4));
      bf16x8 a;
      a[0] = (short)f2b(lo.x); a[1] = (short)f2b(lo.y);
      a[2] = (short)f2b(lo.z); a[3] = (short)f2b(lo.w);
      a[4] = (short)f2b(hi.x); a[5] = (short)f2b(hi.y);
      a[6] = (short)f2b(hi.z); a[7] = (short)f2b(hi.w);
      Af[kc] = a;
    }
  }
  f32x4 acc[4];
  #pragma unroll
  for (int nt = 0; nt < 4; ++nt) {
    f32x4 c = {0.f, 0.f, 0.f, 0.f};
    #pragma unroll
    for (int kc = 0; kc < NKC; ++kc)
      c = mfma16(Af[kc], Bf[nt][kc], c);
    acc[nt] = c;
  }
  #pragma unroll
  for (int j = 0; j < 4; ++j) {
    int m = tile0 + kg * 4 + j;
    if (m < n) {
      size_t base = (size_t)m * 64 + r;
      #pragma unroll
      for (int nt = 0; nt < 4; ++nt)
        out[base + nt * 16] = f2b(fmaxf(acc[nt][j] + bias[nt * 16 + r], 0.f));
    }
  }
}

// ---------------- combo1: part1-blocks || projM4-blocks || projM2-blocks ----------------
// blocks [0,3072): partition round 1.  [3072,4635): proj stay.  [4635,5417): proj diag.
__global__ __launch_bounds__(256) void k_combo1(
    const int* __restrict__ s0, const int* __restrict__ d0,
    const int* __restrict__ s1, const int* __restrict__ d1,
    const int* __restrict__ s2, const int* __restrict__ d2,
    unsigned int* __restrict__ part1, int* __restrict__ gcur1,
    const float* __restrict__ xs, const unsigned short* __restrict__ Wps_b,
    const float* __restrict__ bps, unsigned short* __restrict__ hs_b,
    const float* __restrict__ xd, const unsigned short* __restrict__ Wpd_b,
    const float* __restrict__ bpd, unsigned short* __restrict__ hd_b) {
  __shared__ unsigned int buf[NB1][BC1];
  __shared__ int bcnt[NB1];
  __shared__ int bbase[NB1];
  const int gb = blockIdx.x;
  if (gb >= 3072) {
    if (gb < 3072 + 1563) projM_body<4>(gb - 3072, xs, Wps_b, bps, hs_b, NSTAY);
    else                  projM_body<2>(gb - 4635, xd, Wpd_b, bpd, hd_b, NDIAG);
    return;
  }
  const int ty = gb >> 10;
  const int bx = gb & 1023;
  const int* src; const int* dst; int cpc1;
  if (ty == 0)      { src = s0; dst = d0; cpc1 = (NDIAG + NB1 - 1) / NB1; }
  else if (ty == 1) { src = s1; dst = d1; cpc1 = (NSTAY + NB1 - 1) / NB1; }
  else              { src = s2; dst = d2; cpc1 = (NSTAY + NB1 - 1) / NB1; }
  if (threadIdx.x < NB1) bcnt[threadIdx.x] = 0;
  __syncthreads();
  const int NE4 = NE / 4;
  int i = bx * 256 + threadIdx.x;
  if (i < NE4) {
    i32x4 dd = __builtin_nontemporal_load(reinterpret_cast<const i32x4*>(dst) + i);
    i32x4 ss = __builtin_nontemporal_load(reinterpret_cast<const i32x4*>(src) + i);
    #pragma unroll
    for (int u = 0; u < 4; ++u) {
      int d = dd[u];
      int b = d / cpc1;
      unsigned int pk = ((unsigned int)(d - b * cpc1) << 17) | (unsigned int)ss[u];
      int p = atomicAdd(&bcnt[b], 1);
      if (p < BC1) buf[b][p] = pk;
    }
  }
  __syncthreads();
  if (threadIdx.x < NB1) {
    int c = bcnt[threadIdx.x]; if (c > BC1) c = BC1;
    bcnt[threadIdx.x] = c;
    bbase[threadIdx.x] = atomicAdd(&gcur1[ty * NB1 + threadIdx.x], c);
  }
  __syncthreads();
  #pragma unroll
  for (int b = 0; b < NB1; ++b) {
    int c = bcnt[b], base = bbase[b];
    if (base > P1CAP - c) { int room = P1CAP - base; c = room > 0 ? room : 0; }
    unsigned int* op = part1 + ((size_t)ty * NB1 + b) * P1CAP + base;
    for (int t = threadIdx.x; t < c; t += 256)
      op[t] = buf[b][t];
  }
}

// ---------------- partition round 2: each bin -> 32 sub-bins (512 ranges/type) ----------------
__global__ __launch_bounds__(256) void k_part2(
    const unsigned int* __restrict__ part1, const int* __restrict__ gcur1,
    unsigned int* __restrict__ part2, int* __restrict__ gcur2) {
  __shared__ unsigned int buf[NB2][BC2];
  __shared__ int bcnt[NB2];
  __shared__ int bbase[NB2];
  const int gid = blockIdx.x;
  const int ty  = gid >> 10;
  const int bin = (gid >> 6) & 15;
  const int sub = gid & 63;
  const int cpc2 = (ty == 0) ? 98 : 196;
  int n1 = gcur1[ty * NB1 + bin]; if (n1 > P1CAP) n1 = P1CAP;
  const unsigned int* seg = part1 + ((size_t)ty * NB1 + bin) * P1CAP;
  if (threadIdx.x < NB2) bcnt[threadIdx.x] = 0;
  __syncthreads();
  int i4 = sub * 256 + threadIdx.x;
  int i0 = i4 * 4;
  if (i0 + 4 <= n1) {
    i32x4 vv = *reinterpret_cast<const i32x4*>(seg + i0);
    #pragma unroll
    for (int u = 0; u < 4; ++u) {
      unsigned int v = (unsigned int)vv[u];
      int dcl = (int)(v >> 17);
      int sb = dcl / cpc2;
      unsigned int pk = ((unsigned int)(dcl - sb * cpc2) << 17) | (v & 0x1FFFFu);
      int p = atomicAdd(&bcnt[sb], 1);
      if (p < BC2) buf[sb][p] = pk;
    }
  } else {
    for (int u = 0; u < 4; ++u) {
      int idx = i0 + u;
      if (idx < n1) {
        unsigned int v = seg[idx];
        int dcl = (int)(v >> 17);
        int sb = dcl / cpc2;
        unsigned int pk = ((unsigned int)(dcl - sb * cpc2) << 17) | (v & 0x1FFFFu);
        int p = atomicAdd(&bcnt[sb], 1);
        if (p < BC2) buf[sb][p] = pk;
      }
    }
  }
  __syncthreads();
  if (threadIdx.x < NB2) {
    int c = bcnt[threadIdx.x]; if (c > BC2) c = BC2;
    bcnt[threadIdx.x] = c;
    bbase[threadIdx.x] = atomicAdd(&gcur2[ty * NR + bin * NB2 + threadIdx.x], c);
  }
  __syncthreads();
  #pragma unroll
  for (int b = 0; b < NB2; ++b) {
    int c = bcnt[b], base = bbase[b];
    if (base > P2CAP - c) { int room = P2CAP - base; c = room > 0 ? room : 0; }
    unsigned int* op = part2 + ((size_t)ty * NR + bin * NB2 + b) * P2CAP + base;
    for (int t = threadIdx.x; t < c; t += 256)
      op[t] = buf[b][t];
  }
}

// ---------------- CSR build per range: count -> scan -> sort in LDS -> coalesced flush ----------------
__global__ __launch_bounds__(256) void k_csr(
    unsigned int* __restrict__ part2, const int* __restrict__ gcur2,
    int* __restrict__ offD, int* __restrict__ degD,
    int* __restrict__ off1, int* __restrict__ deg1,
    int* __restrict__ off2, int* __restrict__ deg2) {
  __shared__ int cnt[196];
  __shared__ int cur[196];
  __shared__ unsigned int sorted[P2CAP];
  const int ty = blockIdx.x >> 9;
  const int r  = blockIdx.x & (NR - 1);
  int cpc1, cpc2, nnode; int* off; int* deg;
  if (ty == 0)      { cpc1 = 3125; cpc2 = 98;  nnode = NDIAG; off = offD; deg = degD; }
  else if (ty == 1) { cpc1 = 6250; cpc2 = 196; nnode = NSTAY; off = off1; deg = deg1; }
  else              { cpc1 = 6250; cpc2 = 196; nnode = NSTAY; off = off2; deg = deg2; }
  const int rid = ty * NR + r;
  int n2 = gcur2[rid]; if (n2 > P2CAP) n2 = P2CAP;
  unsigned int* seg = part2 + (size_t)rid * P2CAP;
  for (int i = threadIdx.x; i < cpc2; i += 256) cnt[i] = 0;
  __syncthreads();
  for (int t = threadIdx.x; t < n2; t += 256)
    atomicAdd(&cnt[seg[t] >> 17], 1);
  __syncthreads();
  if (threadIdx.x < 64) {
    int lane = threadIdx.x;
    int c0 = (lane * 4     < cpc2) ? cnt[lane * 4]     : 0;
    int c1 = (lane * 4 + 1 < cpc2) ? cnt[lane * 4 + 1] : 0;
    int c2 = (lane * 4 + 2 < cpc2) ? cnt[lane * 4 + 2] : 0;
    int c3 = (lane * 4 + 3 < cpc2) ? cnt[lane * 4 + 3] : 0;
    int qs = c0 + c1 + c2 + c3;
    int x = qs;
    #pragma unroll
    for (int o = 1; o < 64; o <<= 1) { int y = __shfl_up(x, o); if (lane >= o) x += y; }
    int base = x - qs;
    if (lane * 4     < cpc2) cur[lane * 4]     = base;
    if (lane * 4 + 1 < cpc2) cur[lane * 4 + 1] = base + c0;
    if (lane * 4 + 2 < cpc2) cur[lane * 4 + 2] = base + c0 + c1;
    if (lane * 4 + 3 < cpc2) cur[lane * 4 + 3] = base + c0 + c1 + c2;
  }
  __syncthreads();
  const int bin = r >> 5, sb = r & 31;
  const int node0 = bin * cpc1 + sb * cpc2;
  int dmax = cpc1 - sb * cpc2; if (dmax > cpc2) dmax = cpc2;
  for (int i = threadIdx.x; i < cpc2; i += 256) {
    int node = node0 + i;
    if (i < dmax && node < nnode) {
      off[node] = rid * P2CAP + cur[i];
      deg[node] = cnt[i];
    }
  }
  __syncthreads();
  for (int t = threadIdx.x; t < n2; t += 256) {
    unsigned int v = seg[t];
    int pos = atomicAdd(&cur[v >> 17], 1);
    sorted[pos] = v & 0x1FFFFu;
  }
  __syncthreads();
  for (int t = threadIdx.x; t < n2; t += 256)
    seg[t] = sorted[t];
}

// ---------------- merged gather-mean over CSR: one 16-lane group per node, 8-deep MLP ----------------
__global__ __launch_bounds__(256) void k_gather3(
    const unsigned short* __restrict__ hs, const unsigned short* __restrict__ hd,
    const unsigned int* __restrict__ srt,
    const int* __restrict__ off2, const int* __restrict__ deg2, unsigned short* __restrict__ agg2,
    const int* __restrict__ off1, const int* __restrict__ deg1, unsigned short* __restrict__ agg1,
    const int* __restrict__ offD, const int* __restrict__ degD, unsigned short* __restrict__ aggD,
    int ntot) {
  const int fl = threadIdx.x & 15;                 // feature quad within group
  int gg = (blockIdx.x * 256 + threadIdx.x) >> 4;  // global 16-lane group = one node
  const int ng = (gridDim.x * 256) >> 4;
  for (int gn = gg; gn < ntot; gn += ng) {
    const unsigned short* h; const int* off; const int* deg; unsigned short* agg; int node;
    if (gn < NSTAY)            { h = hs; off = off2; deg = deg2; agg = agg2; node = gn; }
    else if (gn < 2 * NSTAY)   { h = hd; off = off1; deg = deg1; agg = agg1; node = gn - NSTAY; }
    else                       { h = hs; off = offD; deg = degD; agg = aggD; node = gn - 2 * NSTAY; }
    const int e = deg[node];
    const unsigned int* row = srt + off[node];
    float a0x = 0, a0y = 0, a0z = 0, a0w = 0;
    float a1x = 0, a1y = 0, a1z = 0, a1w = 0;
    float a2x = 0, a2y = 0, a2z = 0, a2w = 0;
    float a3x = 0, a3y = 0, a3z = 0, a3w = 0;
    int j = 0;
    for (; j + 8 <= e; j += 8) {
      unsigned int i0 = row[j],     i1 = row[j + 1], i2 = row[j + 2], i3 = row[j + 3];
      unsigned int i4 = row[j + 4], i5 = row[j + 5], i6 = row[j + 6], i7 = row[j + 7];
      ushort4 v0 = *(const ushort4*)(h + (size_t)i0 * 64 + fl * 4);
      ushort4 v1 = *(const ushort4*)(h + (size_t)i1 * 64 + fl * 4);
      ushort4 v2 = *(const ushort4*)(h + (size_t)i2 * 64 + fl * 4);
      ushort4 v3 = *(const ushort4*)(h + (size_t)i3 * 64 + fl * 4);
      ushort4 v4 = *(const ushort4*)(h + (size_t)i4 * 64 + fl * 4);
      ushort4 v5 = *(const ushort4*)(h + (size_t)i5 * 64 + fl * 4);
      ushort4 v6 = *(const ushort4*)(h + (size_t)i6 * 64 + fl * 4);
      ushort4 v7 = *(const ushort4*)(h + (size_t)i7 * 64 + fl * 4);
      a0x += b2f(v0.x); a0y += b2f(v0.y); a0z += b2f(v0.z); a0w += b2f(v0.w);
      a1x += b2f(v1.x); a1y += b2f(v1.y); a1z += b2f(v1.z); a1w += b2f(v1.w);
      a2x += b2f(v2.x); a2y += b2f(v2.y); a2z += b2f(v2.z); a2w += b2f(v2.w);
      a3x += b2f(v3.x); a3y += b2f(v3.y); a3z += b2f(v3.z); a3w += b2f(v3.w);
      a0x += b2f(v4.x); a0y += b2f(v4.y); a0z += b2f(v4.z); a0w += b2f(v4.w);
      a1x += b2f(v5.x); a1y += b2f(v5.y); a1z += b2f(v5.z); a1w += b2f(v5.w);
      a2x += b2f(v6.x); a2y += b2f(v6.y); a2z += b2f(v6.z); a2w += b2f(v6.w);
      a3x += b2f(v7.x); a3y += b2f(v7.y); a3z += b2f(v7.z); a3w += b2f(v7.w);
    }
    if (j + 4 <= e) {
      unsigned int i0 = row[j], i1 = row[j + 1], i2 = row[j + 2], i3 = row[j + 3];
      ushort4 v0 = *(const ushort4*)(h + (size_t)i0 * 64 + fl * 4);
      ushort4 v1 = *(const ushort4*)(h + (size_t)i1 * 64 + fl * 4);
      ushort4 v2 = *(const ushort4*)(h + (size_t)i2 * 64 + fl * 4);
      ushort4 v3 = *(const ushort4*)(h + (size_t)i3 * 64 + fl * 4);
      a0x += b2f(v0.x); a0y += b2f(v0.y); a0z += b2f(v0.z); a0w += b2f(v0.w);
      a1x += b2f(v1.x); a1y += b2f(v1.y); a1z += b2f(v1.z); a1w += b2f(v1.w);
      a2x += b2f(v2.x); a2y += b2f(v2.y); a2z += b2f(v2.z); a2w += b2f(v2.w);
      a3x += b2f(v3.x); a3y += b2f(v3.y); a3z += b2f(v3.z); a3w += b2f(v3.w);
      j += 4;
    }
    for (; j < e; ++j) {
      unsigned int i0 = row[j];
      ushort4 v0 = *(const ushort4*)(h + (size_t)i0 * 64 + fl * 4);
      a0x += b2f(v0.x); a0y += b2f(v0.y); a0z += b2f(v0.z); a0w += b2f(v0.w);
    }
    float ax = (a0x + a1x) + (a2x + a3x);
    float ay = (a0y + a1y) + (a2y + a3y);
    float az = (a0z + a1z) + (a2z + a3z);
    float aw = (a0w + a1w) + (a2w + a3w);
    float inv = (e > 0) ? 1.0f / (float)e : 1.0f;
    ushort4 o = make_ushort4(f2b(ax * inv), f2b(ay * inv), f2b(az * inv), f2b(aw * inv));
    *(ushort4*)(agg + (size_t)node * 64 + fl * 4) = o;
  }
}

// ---------------- stay-side SAGE body (+optional fused classifier) ----------------
template<int CLS>
__device__ __forceinline__ void sage2_body(int blk,
    const unsigned short* __restrict__ agg2b,
    const unsigned short* __restrict__ agg1b,
    unsigned short* hb,
    const unsigned short* __restrict__ W2b, const float* __restrict__ bl2,
    const unsigned short* __restrict__ W1b, const float* __restrict__ bl1,
    const float* __restrict__ g, const float* __restrict__ bln, int n,
    const float* __restrict__ Wcf, const float* __restrict__ bcf,
    float* __restrict__ outp) {
  const int lane = threadIdx.x & 63;
  const int wv   = threadIdx.x >> 6;
  const int r    = lane & 15;
  const int kg   = lane >> 4;
  const int tile0 = (blk * 4 + wv) * 16;
  if (tile0 >= n) return;
  const int node = tile0 + r;
  const bool ok = node < n;
  const size_t rowa = (size_t)node * 64 + kg * 8;
  bf16x8 A20 = {}, A21 = {}, A10 = {}, A11 = {}, H0 = {}, H1 = {};
  if (ok) {
    A20 = ldb8(agg2b + rowa); A21 = ldb8(agg2b + rowa + 32);
    A10 = ldb8(agg1b + rowa); A11 = ldb8(agg1b + rowa + 32);
    H0  = ldb8(hb + rowa);    H1  = ldb8(hb + rowa + 32);
  }
  f32x4 acc2[4], acc1[4];
  #pragma unroll
  for (int nt = 0; nt < 4; ++nt) {
    const unsigned short* wr = W2b + (nt * 16 + r) * 128 + kg * 8;
    f32x4 c = {0.f, 0.f, 0.f, 0.f};
    c = mfma16(A20, ldb8(wr), c);
    c = mfma16(A21, ldb8(wr + 32), c);
    c = mfma16(H0,  ldb8(wr + 64), c);
    c = mfma16(H1,  ldb8(wr + 96), c);
    acc2[nt] = c;
  }
  #pragma unroll
  for (int nt = 0; nt < 4; ++nt) {
    const unsigned short* wr = W1b + (nt * 16 + r) * 128 + kg * 8;
    f32x4 c = {0.f, 0.f, 0.f, 0.f};
    c = mfma16(A10, ldb8(wr), c);
    c = mfma16(A11, ldb8(wr + 32), c);
    c = mfma16(H0,  ldb8(wr + 64), c);
    c = mfma16(H1,  ldb8(wr + 96), c);
    acc1[nt] = c;
  }
  #pragma unroll
  for (int nt = 0; nt < 4; ++nt) {
    float b2 = bl2[nt * 16 + r], b1 = bl1[nt * 16 + r];
    #pragma unroll
    for (int j = 0; j < 4; ++j) { acc2[nt][j] += b2; acc1[nt][j] += b1; }
  }
  float ss2[4], ss1[4];
  #pragma unroll
  for (int j = 0; j < 4; ++j) {
    ss2[j] = acc2[0][j] * acc2[0][j] + acc2[1][j] * acc2[1][j]
           + acc2[2][j] * acc2[2][j] + acc2[3][j] * acc2[3][j];
    ss1[j] = acc1[0][j] * acc1[0][j] + acc1[1][j] * acc1[1][j]
           + acc1[2][j] * acc1[2][j] + acc1[3][j] * acc1[3][j];
  }
  #pragma unroll
  for (int off = 1; off < 16; off <<= 1) {
    #pragma unroll
    for (int j = 0; j < 4; ++j) {
      ss2[j] += __shfl_xor(ss2[j], off);
      ss1[j] += __shfl_xor(ss1[j], off);
    }
  }
  float v[4][4];
  #pragma unroll
  for (int j = 0; j < 4; ++j) {
    float ri2 = 1.0f / fmaxf(sqrtf(ss2[j]), 1e-12f);
    float ri1 = 1.0f / fmaxf(sqrtf(ss1[j]), 1e-12f);
    #pragma unroll
    for (int nt = 0; nt < 4; ++nt)
      v[nt][j] = fmaxf(0.5f * (acc2[nt][j] * ri2 + acc1[nt][j] * ri1), 0.f);
  }
  float s1[4], s2[4];
  #pragma unroll
  for (int j = 0; j < 4; ++j) {
    s1[j] = v[0][j] + v[1][j] + v[2][j] + v[3][j];
    s2[j] = v[0][j] * v[0][j] + v[1][j] * v[1][j] + v[2][j] * v[2][j] + v[3][j] * v[3][j];
  }
  #pragma unroll
  for (int off = 1; off < 16; off <<= 1) {
    #pragma unroll
    for (int j = 0; j < 4; ++j) {
      s1[j] += __shfl_xor(s1[j], off);
      s2[j] += __shfl_xor(s2[j], off);
    }
  }
  if (CLS == 0) {
    #pragma unroll
    for (int j = 0; j < 4; ++j) {
      int m = tile0 + kg * 4 + j;
      if (m >= n) continue;
      float mu  = s1[j] * (1.f / 64.f);
      float var = s2[j] * (1.f / 64.f) - mu * mu;
      float is  = 1.0f / sqrtf(var + 1e-5f);
      size_t base = (size_t)m * 64 + r;
      #pragma unroll
      for (int nt = 0; nt < 4; ++nt)
        hb[base + nt * 16] = f2b((v[nt][j] - mu) * is * g[nt * 16 + r] + bln[nt * 16 + r]);
    }
  } else {
    float wcc[3][4];
    #pragma unroll
    for (int c = 0; c < 3; ++c)
      #pragma unroll
      for (int nt = 0; nt < 4; ++nt) wcc[c][nt] = Wcf[c * 64 + nt * 16 + r];
    #pragma unroll
    for (int j = 0; j < 4; ++j) {
      int m = tile0 + kg * 4 + j;
      float mu  = s1[j] * (1.f / 64.f);
      float var = s2[j] * (1.f / 64.f) - mu * mu;
      float is  = 1.0f / sqrtf(var + 1e-5f);
      float p0 = 0.f, p1 = 0.f, p2 = 0.f;
      #pragma unroll
      for (int nt = 0; nt < 4; ++nt) {
        float hv = (v[nt][j] - mu) * is * g[nt * 16 + r] + bln[nt * 16 + r];
        p0 += hv * wcc[0][nt]; p1 += hv * wcc[1][nt]; p2 += hv * wcc[2][nt];
      }
      #pragma unroll
      for (int off = 1; off < 16; off <<= 1) {
        p0 += __shfl_xor(p0, off);
        p1 += __shfl_xor(p1, off);
        p2 += __shfl_xor(p2, off);
      }
      if (m < n && r < 3) {
        float pr = (r == 0) ? p0 : ((r == 1) ? p1 : p2);
        outp[(size_t)m * 3 + r] = pr + bcf[r];
      }
    }
  }
}

// ---------------- diag-side SAGE body ----------------
__device__ __forceinline__ void sageD_body(int blk,
    const unsigned short* __restrict__ aggb,
    unsigned short* hb,
    const unsigned short* __restrict__ Wb, const float* __restrict__ bl,
    const float* __restrict__ g, const float* __restrict__ bln, int n) {
  const int lane = threadIdx.x & 63;
  const int wv   = threadIdx.x >> 6;
  const int r    = lane & 15;
  const int kg   = lane >> 4;
  const int tile0 = (blk * 4 + wv) * 16;
  if (tile0 >= n) return;
  const int node = tile0 + r;
  const bool ok = node < n;
  const size_t rowa = (size_t)node * 64 + kg * 8;
  bf16x8 A0 = {}, A1 = {}, H0 = {}, H1 = {};
  if (ok) {
    A0 = ldb8(aggb + rowa); A1 = ldb8(aggb + rowa + 32);
    H0 = ldb8(hb + rowa);   H1 = ldb8(hb + rowa + 32);
  }
  f32x4 acc[4];
  #pragma unroll
  for (int nt = 0; nt < 4; ++nt) {
    const unsigned short* wr = Wb + (nt * 16 + r) * 128 + kg * 8;
    f32x4 c = {0.f, 0.f, 0.f, 0.f};
    c = mfma16(A0, ldb8(wr), c);
    c = mfma16(A1, ldb8(wr + 32), c);
    c = mfma16(H0, ldb8(wr + 64), c);
    c = mfma16(H1, ldb8(wr + 96), c);
    acc[nt] = c;
  }
  #pragma unroll
  for (int nt = 0; nt < 4; ++nt) {
    float bb = bl[nt * 16 + r];
    #pragma unroll
    for (int j = 0; j < 4; ++j) acc[nt][j] += bb;
  }
  float ss[4];
  #pragma unroll
  for (int j = 0; j < 4; ++j)
    ss[j] = acc[0][j] * acc[0][j] + acc[1][j] * acc[1][j]
          + acc[2][j] * acc[2][j] + acc[3][j] * acc[3][j];
  #pragma unroll
  for (int off = 1; off < 16; off <<= 1) {
    #pragma unroll
    for (int j = 0; j < 4; ++j) ss[j] += __shfl_xor(ss[j], off);
  }
  float v[4][4];
  #pragma unroll
  for (int j = 0; j < 4; ++j) {
    float ri = 1.0f / fmaxf(sqrtf(ss[j]), 1e-12f);
    #pragma unroll
    for (int nt = 0; nt < 4; ++nt) v[nt][j] = fmaxf(acc[nt][j] * ri, 0.f);
  }
  float s1[4], s2[4];
  #pragma unroll
  for (int j = 0; j < 4; ++j) {
    s1[j] = v[0][j] + v[1][j] + v[2][j] + v[3][j];
    s2[j] = v[0][j] * v[0][j] + v[1][j] * v[1][j] + v[2][j] * v[2][j] + v[3][j] * v[3][j];
  }
  #pragma unroll
  for (int off = 1; off < 16; off <<= 1) {
    #pragma unroll
    for (int j = 0; j < 4; ++j) {
      s1[j] += __shfl_xor(s1[j], off);
      s2[j] += __shfl_xor(s2[j], off);
    }
  }
  #pragma unroll
  for (int j = 0; j < 4; ++j) {
    int m = tile0 + kg * 4 + j;
    if (m >= n) continue;
    float mu  = s1[j] * (1.f / 64.f);
    float var = s2[j] * (1.f / 64.f) - mu * mu;
    float is  = 1.0f / sqrtf(var + 1e-5f);
    size_t base = (size_t)m * 64 + r;
    #pragma unroll
    for (int nt = 0; nt < 4; ++nt)
      hb[base + nt * 16] = f2b((v[nt][j] - mu) * is * g[nt * 16 + r] + bln[nt * 16 + r]);
  }
}

// ---------------- layer-0 node update: stay-blocks || diag-blocks in one launch ----------------
__global__ __launch_bounds__(256) void k_sage_l0(
    const unsigned short* __restrict__ agg2b, const unsigned short* __restrict__ agg1b,
    unsigned short* hs_b,
    const unsigned short* __restrict__ W2b, const float* __restrict__ bl2,
    const unsigned short* __restrict__ W1b, const float* __restrict__ bl1,
    const unsigned short* __restrict__ aggDb, unsigned short* hd_b,
    const unsigned short* __restrict__ W0b, const float* __restrict__ bl0,
    const float* __restrict__ g, const float* __restrict__ bln, int gs) {
  if ((int)blockIdx.x < gs)
    sage2_body<0>(blockIdx.x, agg2b, agg1b, hs_b, W2b, bl2, W1b, bl1,
                  g, bln, NSTAY, nullptr, nullptr, nullptr);
  else
    sageD_body(blockIdx.x - gs, aggDb, hd_b, W0b, bl0, g, bln, NDIAG);
}

// ---------------- layer-1 node update + fused classifier ----------------
__global__ __launch_bounds__(256) void k_sage_l1(
    const unsigned short* __restrict__ agg2b, const unsigned short* __restrict__ agg1b,
    unsigned short* hs_b,
    const unsigned short* __restrict__ W2b, const float* __restrict__ bl2,
    const unsigned short* __restrict__ W1b, const float* __restrict__ bl1,
    const float* __restrict__ g, const float* __restrict__ bln,
    const float* __restrict__ Wcf, const float* __restrict__ bcf,
    float* __restrict__ outp) {
  sage2_body<1>(blockIdx.x, agg2b, agg1b, hs_b, W2b, bl2, W1b, bl1,
                g, bln, NSTAY, Wcf, bcf, outp);
}

extern "C" void kernel_launch(void* const* d_in, const int* in_sizes, int n_in,
                              void* d_out, int out_size, void* d_ws, size_t ws_size,
                              hipStream_t stream) {
  const float* x_stay  = (const float*)d_in[0];
  const float* x_diag  = (const float*)d_in[1];
  const int*   s2d_src = (const int*)d_in[2];
  const int*   s2d_dst = (const int*)d_in[3];
  const int*   d2s_src = (const int*)d_in[4];
  const int*   d2s_dst = (const int*)d_in[5];
  const int*   s2s_src = (const int*)d_in[6];
  const int*   s2s_dst = (const int*)d_in[7];
  const float* Wp_stay = (const float*)d_in[8];
  const float* bp_stay = (const float*)d_in[9];
  const float* Wp_diag = (const float*)d_in[10];
  const float* bp_diag = (const float*)d_in[11];
  const float* Wl      = (const float*)d_in[12];
  const float* bl      = (const float*)d_in[13];
  const float* Wr      = (const float*)d_in[14];
  const float* ln_g    = (const float*)d_in[15];
  const float* ln_b    = (const float*)d_in[16];
  const float* Wc      = (const float*)d_in[17];
  const float* bc      = (const float*)d_in[18];

  // ---- workspace layout (float-slot units) ----
  float* ws = (float*)d_ws;
  unsigned short* hs_b   = (unsigned short*)(ws);             // 6.4M ush
  unsigned short* hd_b   = (unsigned short*)(ws + 3200000);   // 3.2M ush
  unsigned short* agg2_b = (unsigned short*)(ws + 4800000);   // 6.4M ush
  unsigned short* agg1_b = (unsigned short*)(ws + 8000000);   // 6.4M ush
  unsigned short* aggD_b = (unsigned short*)(ws + 11200000);  // 3.2M ush
  unsigned short* Wc6    = (unsigned short*)(ws + 12800000);  // 49152 ush
  unsigned short* Wps_b  = (unsigned short*)(ws + 12825000);  // 8192 ush
  unsigned short* Wpd_b  = (unsigned short*)(ws + 12830000);  // 4096 ush
  unsigned int* part1 = (unsigned int*)(ws + 12835000);       // 3*16*65536 = 3,145,728
  unsigned int* part2 = (unsigned int*)(ws + 15985000);       // 3*512*2400 = 3,686,400
  int* offD  = (int*)(ws + 19675000);                         // 50000
  int* off1  = offD + 50000;                                  // 100000
  int* off2  = off1 + 100000;                                 // 100000
  int* degD  = off2 + 100000;                                 // 50000
  int* deg1  = degD + 50000;                                  // 100000
  int* deg2  = deg1 + 100000;                                 // 100000
  int* gcur1 = deg2 + 100000;                                 // 48
  int* gcur2 = gcur1 + 48;                                    // 1536
  // end ≈ 20.18M slots ≈ 80.7 MB

  const int GS = (NSTAY / 16 + 3) / 4;   // 1563
  const int GD = (NDIAG / 16 + 3) / 4;   // 782

  // ---- weight prep + gcur zeroing ----
  k_prep<<<247, 256, 0, stream>>>(Wp_stay, Wp_diag, Wl, Wr, Wps_b, Wpd_b, Wc6,
                                  gcur1, gcur2);

  // ---- combo: partition round 1 || input projections ----
  k_combo1<<<3072 + GS + GD, 256, 0, stream>>>(
      s2d_src, s2d_dst, d2s_src, d2s_dst, s2s_src, s2s_dst, part1, gcur1,
      x_stay, Wps_b, bp_stay, hs_b,
      x_diag, Wpd_b, bp_diag, hd_b);

  // ---- partition round 2 + per-range CSR sort ----
  k_part2<<<3072, 256, 0, stream>>>(part1, gcur1, part2, gcur2);
  k_csr<<<1536, 256, 0, stream>>>(part2, gcur2, offD, degD, off1, deg1, off2, deg2);

  // ================= layer 0 =================
  {
    const unsigned short* W0 = Wc6;
    const unsigned short* W1 = Wc6 + 8192;
    const unsigned short* W2 = Wc6 + 16384;
    const float* bl0 = bl, *bl1 = bl + 64, *bl2 = bl + 128;
    const float* g = ln_g, *b = ln_b;

    k_gather3<<<4096, 256, 0, stream>>>(hs_b, hd_b, part2,
        off2, deg2, agg2_b, off1, deg1, agg1_b, offD, degD, aggD_b,
        2 * NSTAY + NDIAG);
    k_sage_l0<<<GS + GD, 256, 0, stream>>>(agg2_b, agg1_b, hs_b, W2, bl2, W1, bl1,
        aggD_b, hd_b, W0, bl0, g, b, GS);
  }
  // ================= layer 1 (diag update dead: output depends only on h_stay) =================
  {
    const unsigned short* W1 = Wc6 + 8192 * 4;   // type 1, layer 1
    const unsigned short* W2 = Wc6 + 8192 * 5;   // type 2, layer 1
    const float* bl1 = bl + (3 + 1) * 64;
    const float* bl2 = bl + (3 + 2) * 64;
    const float* g = ln_g + 64, *b = ln_b + 64;

    k_gather3<<<4096, 256, 0, stream>>>(hs_b, hd_b, part2,
        off2, deg2, agg2_b, off1, deg1, agg1_b, offD, degD, aggD_b,
        2 * NSTAY);   // skip dead s2d aggregation
    k_sage_l1<<<GS, 256, 0, stream>>>(agg2_b, agg1_b, hs_b, W2, bl2, W1, bl1,
        g, b, Wc, bc, (float*)d_out);
  }
}